// Round 1
// baseline (554.048 us; speedup 1.0000x reference)
//
#include <hip/hip_runtime.h>
#include <math.h>

#define N_NODES 50000
#define E_RAWN  600000
#define FEAT    64
#define HID     64
#define HEADS   4
#define NSUB    32
#define NGRAPH  128
#define NB_SCAN ((N_NODES + 255) / 256)   // 196

__device__ __forceinline__ float leaky02(float v) { return v >= 0.f ? v : 0.2f * v; }
__device__ __forceinline__ float elu1(float v)    { return v > 0.f ? v : expm1f(v); }

// ---------- Phase A: substructure mean + attention MLP + softmax ----------
__global__ void k_subst_accum(const float* __restrict__ x,
                              float* __restrict__ ssum, float* __restrict__ scnt) {
    __shared__ float lsum[NSUB * FEAT];
    __shared__ float lcnt[NSUB];
    int tid = threadIdx.x;
    for (int i = tid; i < NSUB * FEAT; i += blockDim.x) lsum[i] = 0.f;
    if (tid < NSUB) lcnt[tid] = 0.f;
    __syncthreads();
    const int total = N_NODES * FEAT;
    for (int idx = blockIdx.x * blockDim.x + tid; idx < total; idx += gridDim.x * blockDim.x) {
        int node = idx >> 6, f = idx & 63;
        int sid = (int)x[node * FEAT + 5];
        atomicAdd(&lsum[sid * FEAT + f], x[idx]);
        if (f == 0) atomicAdd(&lcnt[sid], 1.f);
    }
    __syncthreads();
    for (int i = tid; i < NSUB * FEAT; i += blockDim.x) atomicAdd(&ssum[i], lsum[i]);
    if (tid < NSUB) atomicAdd(&scnt[tid], lcnt[tid]);
}

__global__ void k_subst_mlp(const float* __restrict__ ssum, const float* __restrict__ scnt,
                            const float* __restrict__ w_sa1, const float* __restrict__ b_sa1,
                            const float* __restrict__ w_sa2, const float* __restrict__ b_sa2,
                            float* __restrict__ wsub) {
    __shared__ float logits[NSUB];
    int s = threadIdx.x;   // 0..31
    float cnt = fmaxf(scnt[s], 1.f);
    float sm[FEAT];
    for (int k = 0; k < FEAT; k++) sm[k] = ssum[s * FEAT + k] / cnt;
    float logit = b_sa2[0];
    for (int j = 0; j < 32; j++) {
        float hj = b_sa1[j];
        for (int k = 0; k < FEAT; k++) hj += sm[k] * w_sa1[k * 32 + j];
        hj = leaky02(hj);
        logit += hj * w_sa2[j];
    }
    logits[s] = logit;
    __syncthreads();
    float m = -1e30f;
    for (int i = 0; i < NSUB; i++) m = fmaxf(m, logits[i]);
    float dsum = 0.f;
    for (int i = 0; i < NSUB; i++) dsum += expf(logits[i] - m);
    wsub[s] = expf(logits[s] - m) / dsum;
}

// ---------- Phase B: h1 = [x, atom_w] @ W1, plus per-head attention dots ----------
__global__ __launch_bounds__(256) void k_gemm1(const float* __restrict__ x,
                                               const float* __restrict__ wsub,
                                               const float* __restrict__ W1,
                                               const float* __restrict__ att_s1,
                                               const float* __restrict__ att_d1,
                                               float* __restrict__ h1,
                                               float* __restrict__ as1, float* __restrict__ ad1) {
    int wave = threadIdx.x >> 6, lane = threadIdx.x & 63;
    int n = blockIdx.x * 4 + wave;
    if (n >= N_NODES) return;
    float xv = x[(size_t)n * FEAT + lane];
    int sid = (int)__shfl(xv, 5, 64);
    float aw = wsub[sid];
    float4 acc = make_float4(0.f, 0.f, 0.f, 0.f);
    for (int k = 0; k < FEAT; k++) {
        float xk = __shfl(xv, k, 64);
        float4 wr = *(const float4*)(W1 + (size_t)k * 256 + lane * 4);
        acc.x += xk * wr.x; acc.y += xk * wr.y; acc.z += xk * wr.z; acc.w += xk * wr.w;
    }
    {
        float4 wr = *(const float4*)(W1 + (size_t)FEAT * 256 + lane * 4);
        acc.x += aw * wr.x; acc.y += aw * wr.y; acc.z += aw * wr.z; acc.w += aw * wr.w;
    }
    *(float4*)(h1 + (size_t)n * 256 + lane * 4) = acc;
    int h = lane >> 4;
    float4 as = *(const float4*)(att_s1 + lane * 4);
    float4 ad = *(const float4*)(att_d1 + lane * 4);
    float ps = acc.x * as.x + acc.y * as.y + acc.z * as.z + acc.w * as.w;
    float pd = acc.x * ad.x + acc.y * ad.y + acc.z * ad.z + acc.w * ad.w;
    for (int off = 1; off < 16; off <<= 1) {
        ps += __shfl_xor(ps, off, 64);
        pd += __shfl_xor(pd, off, 64);
    }
    if ((lane & 15) == 0) { as1[n * 4 + h] = ps; ad1[n * 4 + h] = pd; }
}

// ---------- CSR build (by dst) ----------
__global__ void k_count(const int* __restrict__ dst, int* __restrict__ cnt) {
    int e = blockIdx.x * blockDim.x + threadIdx.x;
    if (e < E_RAWN) atomicAdd(&cnt[dst[e]], 1);
}

__global__ void k_scan1(const int* __restrict__ cnt, int* __restrict__ offs, int* __restrict__ bsum) {
    __shared__ int sd[256];
    int tid = threadIdx.x;
    int i = blockIdx.x * 256 + tid;
    int v = (i < N_NODES) ? cnt[i] : 0;
    sd[tid] = v;
    for (int off = 1; off < 256; off <<= 1) {
        __syncthreads();
        int t = (tid >= off) ? sd[tid - off] : 0;
        __syncthreads();
        sd[tid] += t;
    }
    __syncthreads();
    if (i < N_NODES) offs[i] = sd[tid] - v;
    if (tid == 255) bsum[blockIdx.x] = sd[255];
}

__global__ void k_scan2(int* __restrict__ bsum, int nb) {
    __shared__ int sd[256];
    int tid = threadIdx.x;
    int v = (tid < nb) ? bsum[tid] : 0;
    sd[tid] = v;
    for (int off = 1; off < 256; off <<= 1) {
        __syncthreads();
        int t = (tid >= off) ? sd[tid - off] : 0;
        __syncthreads();
        sd[tid] += t;
    }
    __syncthreads();
    if (tid < nb) bsum[tid] = sd[tid] - v;
}

__global__ void k_scan3(int* __restrict__ offs, const int* __restrict__ bsum) {
    int i = blockIdx.x * 256 + threadIdx.x;
    if (i < N_NODES) offs[i] += bsum[blockIdx.x];
    if (blockIdx.x == 0 && threadIdx.x == 0) offs[N_NODES] = E_RAWN;
}

__global__ void k_scatter(const int* __restrict__ src, const int* __restrict__ dst,
                          const int* __restrict__ offs, int* __restrict__ cur,
                          int* __restrict__ esrc) {
    int e = blockIdx.x * blockDim.x + threadIdx.x;
    if (e < E_RAWN) {
        int d = dst[e];
        int pos = offs[d] + atomicAdd(&cur[d], 1);
        esrc[pos] = src[e];
    }
}

// ---------- Phase D: GAT layer 1 aggregation (online softmax) + bias + ELU ----------
__global__ __launch_bounds__(256) void k_gat1(const float* __restrict__ h1,
                                              const float* __restrict__ as1,
                                              const float* __restrict__ ad1,
                                              const int* __restrict__ offs,
                                              const int* __restrict__ esrc,
                                              const float* __restrict__ b1,
                                              float* __restrict__ hact) {
    int wave = threadIdx.x >> 6, lane = threadIdx.x & 63;
    int i = blockIdx.x * 4 + wave;
    if (i >= N_NODES) return;
    int h = lane >> 4;
    float adv = ad1[i * 4 + h];
    float e0 = leaky02(as1[i * 4 + h] + adv);
    float m = e0, d = 1.f;
    float4 acc = *(const float4*)(h1 + (size_t)i * 256 + lane * 4);   // self loop, weight exp(0)=1
    int beg = offs[i], end = offs[i + 1];
    for (int p = beg; p < end; p++) {
        int s = esrc[p];
        float e = leaky02(as1[s * 4 + h] + adv);
        float mn = fmaxf(m, e);
        float sc = expf(m - mn);
        float w  = expf(e - mn);
        float4 hs = *(const float4*)(h1 + (size_t)s * 256 + lane * 4);
        d = d * sc + w;
        acc.x = acc.x * sc + w * hs.x;
        acc.y = acc.y * sc + w * hs.y;
        acc.z = acc.z * sc + w * hs.z;
        acc.w = acc.w * sc + w * hs.w;
        m = mn;
    }
    float inv = 1.f / (d + 1e-16f);
    float4 bb = *(const float4*)(b1 + lane * 4);
    float4 r;
    r.x = elu1(acc.x * inv + bb.x);
    r.y = elu1(acc.y * inv + bb.y);
    r.z = elu1(acc.z * inv + bb.z);
    r.w = elu1(acc.w * inv + bb.w);
    *(float4*)(hact + (size_t)i * 256 + lane * 4) = r;
}

// ---------- Phase E: h2 = hact @ W2, plus layer-2 attention dots ----------
__global__ __launch_bounds__(256) void k_gemm2(const float* __restrict__ hact,
                                               const float* __restrict__ W2,
                                               const float* __restrict__ att_s2,
                                               const float* __restrict__ att_d2,
                                               float* __restrict__ h2,
                                               float* __restrict__ as2, float* __restrict__ ad2) {
    __shared__ float row[4][256];
    int wave = threadIdx.x >> 6, lane = threadIdx.x & 63;
    int n = blockIdx.x * 4 + wave;
    bool valid = n < N_NODES;
    if (valid) {
        float4 part = *(const float4*)(hact + (size_t)n * 256 + lane * 4);
        *(float4*)&row[wave][lane * 4] = part;
    }
    __syncthreads();
    if (!valid) return;
    float acc = 0.f;
    for (int k = 0; k < 256; k++) acc += row[wave][k] * W2[(size_t)k * 64 + lane];
    h2[(size_t)n * 64 + lane] = acc;
    float ps = acc * att_s2[lane];
    float pd = acc * att_d2[lane];
    for (int off = 1; off < 64; off <<= 1) {
        ps += __shfl_xor(ps, off, 64);
        pd += __shfl_xor(pd, off, 64);
    }
    if (lane == 0) { as2[n] = ps; ad2[n] = pd; }
}

// ---------- Phase F: GAT layer 2 aggregation + bias + pool ----------
__global__ __launch_bounds__(256) void k_gat2(const float* __restrict__ h2,
                                              const float* __restrict__ as2,
                                              const float* __restrict__ ad2,
                                              const int* __restrict__ offs,
                                              const int* __restrict__ esrc,
                                              const float* __restrict__ b2,
                                              const int* __restrict__ batch,
                                              float* __restrict__ g) {
    int wave = threadIdx.x >> 6, lane = threadIdx.x & 63;
    int i = blockIdx.x * 4 + wave;
    if (i >= N_NODES) return;
    float adv = ad2[i];
    float e0 = leaky02(as2[i] + adv);
    float m = e0, d = 1.f;
    float acc = h2[(size_t)i * 64 + lane];
    int beg = offs[i], end = offs[i + 1];
    for (int p = beg; p < end; p++) {
        int s = esrc[p];
        float e = leaky02(as2[s] + adv);
        float mn = fmaxf(m, e);
        float sc = expf(m - mn);
        float w  = expf(e - mn);
        float hs = h2[(size_t)s * 64 + lane];
        d = d * sc + w;
        acc = acc * sc + w * hs;
        m = mn;
    }
    float r = acc / (d + 1e-16f) + b2[lane];
    atomicAdd(&g[(size_t)batch[i] * 64 + lane], r);
}

// ---------- Phase H: prediction head ----------
__global__ void k_head(const float* __restrict__ g,
                       const float* __restrict__ Wp1, const float* __restrict__ bp1,
                       const float* __restrict__ Wp2, const float* __restrict__ bp2,
                       float* __restrict__ out) {
    int t = threadIdx.x;
    if (t >= NGRAPH) return;
    float acc = bp2[0];
    for (int j = 0; j < 32; j++) {
        float hj = bp1[j];
        for (int k = 0; k < 64; k++) hj += g[(size_t)t * 64 + k] * Wp1[k * 32 + j];
        hj = elu1(hj);
        acc += hj * Wp2[j];
    }
    out[t] = acc;
}

extern "C" void kernel_launch(void* const* d_in, const int* in_sizes, int n_in,
                              void* d_out, int out_size, void* d_ws, size_t ws_size,
                              hipStream_t stream) {
    const float* x      = (const float*)d_in[0];
    const int*   edge   = (const int*)d_in[1];
    const int*   batch  = (const int*)d_in[2];
    const float* w_sa1  = (const float*)d_in[3];
    const float* b_sa1  = (const float*)d_in[4];
    const float* w_sa2  = (const float*)d_in[5];
    const float* b_sa2  = (const float*)d_in[6];
    const float* W1     = (const float*)d_in[7];
    const float* att_s1 = (const float*)d_in[8];
    const float* att_d1 = (const float*)d_in[9];
    const float* b1     = (const float*)d_in[10];
    const float* W2     = (const float*)d_in[11];
    const float* att_s2 = (const float*)d_in[12];
    const float* att_d2 = (const float*)d_in[13];
    const float* b2     = (const float*)d_in[14];
    const float* Wp1    = (const float*)d_in[15];
    const float* bp1    = (const float*)d_in[16];
    const float* Wp2    = (const float*)d_in[17];
    const float* bp2    = (const float*)d_in[18];
    float* out = (float*)d_out;

    const int* e_src = edge;
    const int* e_dst = edge + E_RAWN;

    // workspace carve-up (all 256B aligned)
    char* base = (char*)d_ws;
    size_t off = 0;
    auto alloc = [&](size_t bytes) -> void* {
        void* p = base + off;
        off = (off + bytes + 255) & ~(size_t)255;
        return p;
    };
    float* ssum   = (float*)alloc((NSUB * FEAT + NSUB) * 4);  // ssum + scnt contiguous
    float* scnt   = ssum + NSUB * FEAT;
    float* wsub   = (float*)alloc(NSUB * 4);
    float* as1    = (float*)alloc((size_t)N_NODES * 4 * 4);
    float* ad1    = (float*)alloc((size_t)N_NODES * 4 * 4);
    float* as2    = (float*)alloc((size_t)N_NODES * 4);
    float* ad2    = (float*)alloc((size_t)N_NODES * 4);
    int*   counts = (int*)alloc((size_t)N_NODES * 2 * 4);     // counts + cursor contiguous
    int*   cursor = counts + N_NODES;
    int*   offs   = (int*)alloc((size_t)(N_NODES + 1) * 4);
    int*   bsum   = (int*)alloc(256 * 4);
    int*   esrc   = (int*)alloc((size_t)E_RAWN * 4);
    float* gpool  = (float*)alloc((size_t)NGRAPH * HID * 4);
    float* h1     = (float*)alloc((size_t)N_NODES * 256 * 4);
    float* hact   = (float*)alloc((size_t)N_NODES * 256 * 4);
    float* h2     = h1;   // overlay: h1 dead after k_gat1

    (void)hipMemsetAsync(ssum,   0, (NSUB * FEAT + NSUB) * 4, stream);
    (void)hipMemsetAsync(counts, 0, (size_t)N_NODES * 2 * 4, stream);
    (void)hipMemsetAsync(gpool,  0, (size_t)NGRAPH * HID * 4, stream);

    k_subst_accum<<<256, 256, 0, stream>>>(x, ssum, scnt);
    k_subst_mlp<<<1, 32, 0, stream>>>(ssum, scnt, w_sa1, b_sa1, w_sa2, b_sa2, wsub);
    k_gemm1<<<(N_NODES + 3) / 4, 256, 0, stream>>>(x, wsub, W1, att_s1, att_d1, h1, as1, ad1);

    k_count<<<(E_RAWN + 255) / 256, 256, 0, stream>>>(e_dst, counts);
    k_scan1<<<NB_SCAN, 256, 0, stream>>>(counts, offs, bsum);
    k_scan2<<<1, 256, 0, stream>>>(bsum, NB_SCAN);
    k_scan3<<<NB_SCAN, 256, 0, stream>>>(offs, bsum);
    k_scatter<<<(E_RAWN + 255) / 256, 256, 0, stream>>>(e_src, e_dst, offs, cursor, esrc);

    k_gat1<<<(N_NODES + 3) / 4, 256, 0, stream>>>(h1, as1, ad1, offs, esrc, b1, hact);
    k_gemm2<<<(N_NODES + 3) / 4, 256, 0, stream>>>(hact, W2, att_s2, att_d2, h2, as2, ad2);
    k_gat2<<<(N_NODES + 3) / 4, 256, 0, stream>>>(h2, as2, ad2, offs, esrc, b2, batch, gpool);
    k_head<<<1, 128, 0, stream>>>(gpool, Wp1, bp1, Wp2, bp2, out);
}

// Round 2
// 525.172 us; speedup vs baseline: 1.0550x; 1.0550x over previous
//
#include <hip/hip_runtime.h>
#include <math.h>

#define N_NODES 50000
#define E_RAWN  600000
#define FEAT    64
#define HID     64
#define HEADS   4
#define NSUB    32
#define NGRAPH  128
#define NB_SCAN ((N_NODES + 255) / 256)   // 196

__device__ __forceinline__ float leaky02(float v) { return v >= 0.f ? v : 0.2f * v; }
__device__ __forceinline__ float elu1(float v)    { return v > 0.f ? v : expm1f(v); }

// ---------- Phase A: substructure mean + attention MLP + softmax ----------
__global__ void k_subst_accum(const float* __restrict__ x,
                              float* __restrict__ ssum, float* __restrict__ scnt) {
    __shared__ float lsum[NSUB * FEAT];
    __shared__ float lcnt[NSUB];
    int tid = threadIdx.x;
    for (int i = tid; i < NSUB * FEAT; i += blockDim.x) lsum[i] = 0.f;
    if (tid < NSUB) lcnt[tid] = 0.f;
    __syncthreads();
    const int total = N_NODES * FEAT;
    for (int idx = blockIdx.x * blockDim.x + tid; idx < total; idx += gridDim.x * blockDim.x) {
        int node = idx >> 6, f = idx & 63;
        int sid = (int)x[node * FEAT + 5];
        atomicAdd(&lsum[sid * FEAT + f], x[idx]);
        if (f == 0) atomicAdd(&lcnt[sid], 1.f);
    }
    __syncthreads();
    for (int i = tid; i < NSUB * FEAT; i += blockDim.x) atomicAdd(&ssum[i], lsum[i]);
    if (tid < NSUB) atomicAdd(&scnt[tid], lcnt[tid]);
}

__global__ void k_subst_mlp(const float* __restrict__ ssum, const float* __restrict__ scnt,
                            const float* __restrict__ w_sa1, const float* __restrict__ b_sa1,
                            const float* __restrict__ w_sa2, const float* __restrict__ b_sa2,
                            float* __restrict__ wsub) {
    __shared__ float logits[NSUB];
    int s = threadIdx.x;   // 0..31
    float cnt = fmaxf(scnt[s], 1.f);
    float sm[FEAT];
    for (int k = 0; k < FEAT; k++) sm[k] = ssum[s * FEAT + k] / cnt;
    float logit = b_sa2[0];
    for (int j = 0; j < 32; j++) {
        float hj = b_sa1[j];
        for (int k = 0; k < FEAT; k++) hj += sm[k] * w_sa1[k * 32 + j];
        hj = leaky02(hj);
        logit += hj * w_sa2[j];
    }
    logits[s] = logit;
    __syncthreads();
    float m = -1e30f;
    for (int i = 0; i < NSUB; i++) m = fmaxf(m, logits[i]);
    float dsum = 0.f;
    for (int i = 0; i < NSUB; i++) dsum += expf(logits[i] - m);
    wsub[s] = expf(logits[s] - m) / dsum;
}

// ---------- Phase B: h1 = [x, atom_w] @ W1 (register-tiled, LDS x-tile) ----------
// Block: 256 threads, 64 nodes. Thread: m = t&31 owns cols m*8..m*8+7,
// q = t>>5 owns nodes q*8..q*8+7. accs[8 cols][8 nodes].
__global__ __launch_bounds__(256) void k_gemm1(const float* __restrict__ x,
                                               const float* __restrict__ wsub,
                                               const float* __restrict__ W1,
                                               const float* __restrict__ att_s1,
                                               const float* __restrict__ att_d1,
                                               float* __restrict__ h1,
                                               float* __restrict__ as1, float* __restrict__ ad1) {
    __shared__ float xs[65][68];   // [k][node], padded: 68*4=272B rows (16B aligned)
    int t = threadIdx.x;
    int gbase = blockIdx.x * 64;
    // stage x tile transposed, zero-fill OOB
    for (int idx = t; idx < 64 * 64; idx += 256) {
        int n = idx >> 6, f = idx & 63;
        int g = gbase + n;
        xs[f][n] = (g < N_NODES) ? x[(size_t)g * FEAT + f] : 0.f;
    }
    __syncthreads();
    if (t < 64) {
        int sid = (int)xs[5][t];
        xs[64][t] = wsub[sid & (NSUB - 1)];
    }
    __syncthreads();

    int m = t & 31, q = t >> 5;
    int c0 = m * 8, q8 = q * 8;
    float accs[64];
    #pragma unroll
    for (int i = 0; i < 64; ++i) accs[i] = 0.f;

    for (int k = 0; k < 65; ++k) {
        float4 wa = *(const float4*)(W1 + (size_t)k * 256 + c0);
        float4 wb = *(const float4*)(W1 + (size_t)k * 256 + c0 + 4);
        float4 xa = *(const float4*)(&xs[k][q8]);
        float4 xb = *(const float4*)(&xs[k][q8 + 4]);
        float wv[8] = {wa.x, wa.y, wa.z, wa.w, wb.x, wb.y, wb.z, wb.w};
        float xv[8] = {xa.x, xa.y, xa.z, xa.w, xb.x, xb.y, xb.z, xb.w};
        #pragma unroll
        for (int c = 0; c < 8; ++c)
            #pragma unroll
            for (int j = 0; j < 8; ++j)
                accs[c * 8 + j] += wv[c] * xv[j];
    }

    float atts[8], attd[8];
    #pragma unroll
    for (int c = 0; c < 8; ++c) { atts[c] = att_s1[c0 + c]; attd[c] = att_d1[c0 + c]; }
    int h = m >> 3;
    #pragma unroll
    for (int j = 0; j < 8; ++j) {
        int node = gbase + q8 + j;
        float ps = 0.f, pd = 0.f;
        #pragma unroll
        for (int c = 0; c < 8; ++c) { ps += accs[c * 8 + j] * atts[c]; pd += accs[c * 8 + j] * attd[c]; }
        ps += __shfl_xor(ps, 1, 64); pd += __shfl_xor(pd, 1, 64);
        ps += __shfl_xor(ps, 2, 64); pd += __shfl_xor(pd, 2, 64);
        ps += __shfl_xor(ps, 4, 64); pd += __shfl_xor(pd, 4, 64);
        if (node < N_NODES) {
            float4 lo = make_float4(accs[0 * 8 + j], accs[1 * 8 + j], accs[2 * 8 + j], accs[3 * 8 + j]);
            float4 hi = make_float4(accs[4 * 8 + j], accs[5 * 8 + j], accs[6 * 8 + j], accs[7 * 8 + j]);
            *(float4*)(h1 + (size_t)node * 256 + c0) = lo;
            *(float4*)(h1 + (size_t)node * 256 + c0 + 4) = hi;
            if ((m & 7) == 0) { as1[node * 4 + h] = ps; ad1[node * 4 + h] = pd; }
        }
    }
}

// ---------- CSR build (by dst) ----------
__global__ void k_count(const int* __restrict__ dst, int* __restrict__ cnt) {
    int e = blockIdx.x * blockDim.x + threadIdx.x;
    if (e < E_RAWN) atomicAdd(&cnt[dst[e]], 1);
}

__global__ void k_scan1(const int* __restrict__ cnt, int* __restrict__ offs, int* __restrict__ bsum) {
    __shared__ int sd[256];
    int tid = threadIdx.x;
    int i = blockIdx.x * 256 + tid;
    int v = (i < N_NODES) ? cnt[i] : 0;
    sd[tid] = v;
    for (int off = 1; off < 256; off <<= 1) {
        __syncthreads();
        int tv = (tid >= off) ? sd[tid - off] : 0;
        __syncthreads();
        sd[tid] += tv;
    }
    __syncthreads();
    if (i < N_NODES) offs[i] = sd[tid] - v;
    if (tid == 255) bsum[blockIdx.x] = sd[255];
}

__global__ void k_scan2(int* __restrict__ bsum, int nb) {
    __shared__ int sd[256];
    int tid = threadIdx.x;
    int v = (tid < nb) ? bsum[tid] : 0;
    sd[tid] = v;
    for (int off = 1; off < 256; off <<= 1) {
        __syncthreads();
        int tv = (tid >= off) ? sd[tid - off] : 0;
        __syncthreads();
        sd[tid] += tv;
    }
    __syncthreads();
    if (tid < nb) bsum[tid] = sd[tid] - v;
}

__global__ void k_scan3(int* __restrict__ offs, const int* __restrict__ bsum) {
    int i = blockIdx.x * 256 + threadIdx.x;
    if (i < N_NODES) offs[i] += bsum[blockIdx.x];
    if (blockIdx.x == 0 && threadIdx.x == 0) offs[N_NODES] = E_RAWN;
}

__global__ void k_scatter(const int* __restrict__ src, const int* __restrict__ dst,
                          const int* __restrict__ offs, int* __restrict__ cur,
                          int* __restrict__ esrc) {
    int e = blockIdx.x * blockDim.x + threadIdx.x;
    if (e < E_RAWN) {
        int d = dst[e];
        int pos = offs[d] + atomicAdd(&cur[d], 1);
        esrc[pos] = src[e];
    }
}

// ---------- Phase D: GAT layer 1 aggregation, two-pass (no max-sub) ----------
__global__ __launch_bounds__(256) void k_gat1(const float* __restrict__ h1,
                                              const float* __restrict__ as1,
                                              const float* __restrict__ ad1,
                                              const int* __restrict__ offs,
                                              const int* __restrict__ esrc,
                                              const float* __restrict__ b1,
                                              float* __restrict__ hact) {
    int wave = threadIdx.x >> 6, lane = threadIdx.x & 63;
    int i = blockIdx.x * 4 + wave;
    if (i >= N_NODES) return;
    int beg = offs[i], end = offs[i + 1];
    // pass A: denominator per head (lanes: edge-slot = lane>>2, head hh = lane&3)
    int hh = lane & 3;
    float adv_hh = ad1[i * 4 + hh];
    float dl = 0.f;
    for (int p0 = beg; p0 < end; p0 += 16) {
        int p = p0 + (lane >> 2);
        if (p < end) {
            int s = esrc[p];
            dl += expf(leaky02(as1[s * 4 + hh] + adv_hh));
        }
    }
    dl += __shfl_xor(dl, 4, 64);
    dl += __shfl_xor(dl, 8, 64);
    dl += __shfl_xor(dl, 16, 64);
    dl += __shfl_xor(dl, 32, 64);
    dl += expf(leaky02(as1[i * 4 + hh] + adv_hh));   // self loop
    int h = lane >> 4;
    float d = __shfl(dl, h, 4);                       // pull my head's denom
    float inv = 1.f / (d + 1e-16f);
    // pass B: weighted gather
    float adv = ad1[i * 4 + h];
    float w0 = expf(leaky02(as1[i * 4 + h] + adv));
    float4 hv = *(const float4*)(h1 + (size_t)i * 256 + lane * 4);
    float4 acc = make_float4(w0 * hv.x, w0 * hv.y, w0 * hv.z, w0 * hv.w);
    int p = beg;
    for (; p + 1 < end; p += 2) {
        int s0 = esrc[p], s1 = esrc[p + 1];
        float w1_ = expf(leaky02(as1[s0 * 4 + h] + adv));
        float w2_ = expf(leaky02(as1[s1 * 4 + h] + adv));
        float4 ha = *(const float4*)(h1 + (size_t)s0 * 256 + lane * 4);
        float4 hb = *(const float4*)(h1 + (size_t)s1 * 256 + lane * 4);
        acc.x += w1_ * ha.x + w2_ * hb.x;
        acc.y += w1_ * ha.y + w2_ * hb.y;
        acc.z += w1_ * ha.z + w2_ * hb.z;
        acc.w += w1_ * ha.w + w2_ * hb.w;
    }
    if (p < end) {
        int s0 = esrc[p];
        float w1_ = expf(leaky02(as1[s0 * 4 + h] + adv));
        float4 ha = *(const float4*)(h1 + (size_t)s0 * 256 + lane * 4);
        acc.x += w1_ * ha.x; acc.y += w1_ * ha.y; acc.z += w1_ * ha.z; acc.w += w1_ * ha.w;
    }
    float4 bb = *(const float4*)(b1 + lane * 4);
    float4 r;
    r.x = elu1(acc.x * inv + bb.x);
    r.y = elu1(acc.y * inv + bb.y);
    r.z = elu1(acc.z * inv + bb.z);
    r.w = elu1(acc.w * inv + bb.w);
    *(float4*)(hact + (size_t)i * 256 + lane * 4) = r;
}

// ---------- Phase E: h2 = hact @ W2 (register-tiled, LDS tile) ----------
// Block: 256 threads, 32 nodes. Thread: m = t&7 owns cols m*8..m*8+7, node nl = t>>3.
__global__ __launch_bounds__(256) void k_gemm2(const float* __restrict__ hact,
                                               const float* __restrict__ W2,
                                               const float* __restrict__ att_s2,
                                               const float* __restrict__ att_d2,
                                               float* __restrict__ h2,
                                               float* __restrict__ as2, float* __restrict__ ad2) {
    __shared__ float hs[32][260];   // [node][k], 260*4=1040B rows (16B aligned)
    int t = threadIdx.x;
    int gbase = blockIdx.x * 32;
    for (int idx = t; idx < 32 * 256; idx += 256) {
        int n = idx >> 8, k = idx & 255;
        int g = gbase + n;
        hs[n][k] = (g < N_NODES) ? hact[(size_t)g * 256 + k] : 0.f;
    }
    __syncthreads();

    int m = t & 7, nl = t >> 3;
    int node = gbase + nl;
    int c0 = m * 8;
    float acc[8];
    #pragma unroll
    for (int i = 0; i < 8; ++i) acc[i] = 0.f;

    for (int kk = 0; kk < 64; ++kk) {
        float4 xv = *(const float4*)(&hs[nl][kk * 4]);
        float xa[4] = {xv.x, xv.y, xv.z, xv.w};
        #pragma unroll
        for (int jj = 0; jj < 4; ++jj) {
            int k = kk * 4 + jj;
            float4 wa = *(const float4*)(W2 + (size_t)k * 64 + c0);
            float4 wb = *(const float4*)(W2 + (size_t)k * 64 + c0 + 4);
            acc[0] += xa[jj] * wa.x; acc[1] += xa[jj] * wa.y;
            acc[2] += xa[jj] * wa.z; acc[3] += xa[jj] * wa.w;
            acc[4] += xa[jj] * wb.x; acc[5] += xa[jj] * wb.y;
            acc[6] += xa[jj] * wb.z; acc[7] += xa[jj] * wb.w;
        }
    }

    float ps = 0.f, pd = 0.f;
    #pragma unroll
    for (int c = 0; c < 8; ++c) { ps += acc[c] * att_s2[c0 + c]; pd += acc[c] * att_d2[c0 + c]; }
    ps += __shfl_xor(ps, 1, 64); pd += __shfl_xor(pd, 1, 64);
    ps += __shfl_xor(ps, 2, 64); pd += __shfl_xor(pd, 2, 64);
    ps += __shfl_xor(ps, 4, 64); pd += __shfl_xor(pd, 4, 64);
    if (node < N_NODES) {
        *(float4*)(h2 + (size_t)node * 64 + c0)     = make_float4(acc[0], acc[1], acc[2], acc[3]);
        *(float4*)(h2 + (size_t)node * 64 + c0 + 4) = make_float4(acc[4], acc[5], acc[6], acc[7]);
        if (m == 0) { as2[node] = ps; ad2[node] = pd; }
    }
}

// ---------- Phase F: GAT layer 2 aggregation, two-pass (no max-sub), no bias ----------
__global__ __launch_bounds__(256) void k_gat2(const float* __restrict__ h2,
                                              const float* __restrict__ as2,
                                              const float* __restrict__ ad2,
                                              const int* __restrict__ offs,
                                              const int* __restrict__ esrc,
                                              float* __restrict__ rbuf) {
    int wave = threadIdx.x >> 6, lane = threadIdx.x & 63;
    int i = blockIdx.x * 4 + wave;
    if (i >= N_NODES) return;
    int beg = offs[i], end = offs[i + 1];
    float adv = ad2[i];
    float e0 = leaky02(as2[i] + adv);
    float dl = 0.f;
    for (int p0 = beg; p0 < end; p0 += 64) {
        int p = p0 + lane;
        if (p < end) dl += expf(leaky02(as2[esrc[p]] + adv));
    }
    dl += __shfl_xor(dl, 1, 64);
    dl += __shfl_xor(dl, 2, 64);
    dl += __shfl_xor(dl, 4, 64);
    dl += __shfl_xor(dl, 8, 64);
    dl += __shfl_xor(dl, 16, 64);
    dl += __shfl_xor(dl, 32, 64);
    float w0 = expf(e0);
    float d = dl + w0;
    float inv = 1.f / (d + 1e-16f);
    float acc = w0 * h2[(size_t)i * 64 + lane];
    int p = beg;
    for (; p + 1 < end; p += 2) {
        int s0 = esrc[p], s1 = esrc[p + 1];
        float wA = expf(leaky02(as2[s0] + adv));
        float wB = expf(leaky02(as2[s1] + adv));
        float hA = h2[(size_t)s0 * 64 + lane];
        float hB = h2[(size_t)s1 * 64 + lane];
        acc += wA * hA + wB * hB;
    }
    if (p < end) {
        int s0 = esrc[p];
        acc += expf(leaky02(as2[s0] + adv)) * h2[(size_t)s0 * 64 + lane];
    }
    rbuf[(size_t)i * 64 + lane] = acc * inv;
}

// ---------- Phase G: pool per graph (batch sorted, binary search ranges) ----------
__device__ __forceinline__ int lower_bound_i(const int* a, int n, int v) {
    int lo = 0, hi = n;
    while (lo < hi) { int mid = (lo + hi) >> 1; if (a[mid] < v) lo = mid + 1; else hi = mid; }
    return lo;
}

__global__ void k_pool(const float* __restrict__ rbuf, const int* __restrict__ batch,
                       const float* __restrict__ b2, float* __restrict__ g) {
    __shared__ float red[4][64];
    int b = blockIdx.x;
    int lo = lower_bound_i(batch, N_NODES, b);
    int hi = lower_bound_i(batch, N_NODES, b + 1);
    int c = threadIdx.x & 63, rg = threadIdx.x >> 6;
    float s = 0.f;
    for (int r = lo + rg; r < hi; r += 4) s += rbuf[(size_t)r * 64 + c];
    red[rg][c] = s;
    __syncthreads();
    if (rg == 0) {
        float tot = red[0][c] + red[1][c] + red[2][c] + red[3][c] + (float)(hi - lo) * b2[c];
        g[(size_t)b * 64 + c] = tot;
    }
}

// ---------- Phase H: prediction head ----------
__global__ void k_head(const float* __restrict__ g,
                       const float* __restrict__ Wp1, const float* __restrict__ bp1,
                       const float* __restrict__ Wp2, const float* __restrict__ bp2,
                       float* __restrict__ out) {
    int t = threadIdx.x;
    if (t >= NGRAPH) return;
    float acc = bp2[0];
    for (int j = 0; j < 32; j++) {
        float hj = bp1[j];
        for (int k = 0; k < 64; k++) hj += g[(size_t)t * 64 + k] * Wp1[k * 32 + j];
        hj = elu1(hj);
        acc += hj * Wp2[j];
    }
    out[t] = acc;
}

extern "C" void kernel_launch(void* const* d_in, const int* in_sizes, int n_in,
                              void* d_out, int out_size, void* d_ws, size_t ws_size,
                              hipStream_t stream) {
    const float* x      = (const float*)d_in[0];
    const int*   edge   = (const int*)d_in[1];
    const int*   batch  = (const int*)d_in[2];
    const float* w_sa1  = (const float*)d_in[3];
    const float* b_sa1  = (const float*)d_in[4];
    const float* w_sa2  = (const float*)d_in[5];
    const float* b_sa2  = (const float*)d_in[6];
    const float* W1     = (const float*)d_in[7];
    const float* att_s1 = (const float*)d_in[8];
    const float* att_d1 = (const float*)d_in[9];
    const float* b1     = (const float*)d_in[10];
    const float* W2     = (const float*)d_in[11];
    const float* att_s2 = (const float*)d_in[12];
    const float* att_d2 = (const float*)d_in[13];
    const float* b2     = (const float*)d_in[14];
    const float* Wp1    = (const float*)d_in[15];
    const float* bp1    = (const float*)d_in[16];
    const float* Wp2    = (const float*)d_in[17];
    const float* bp2    = (const float*)d_in[18];
    float* out = (float*)d_out;

    const int* e_src = edge;
    const int* e_dst = edge + E_RAWN;

    char* base = (char*)d_ws;
    size_t off = 0;
    auto alloc = [&](size_t bytes) -> void* {
        void* p = base + off;
        off = (off + bytes + 255) & ~(size_t)255;
        return p;
    };
    float* ssum   = (float*)alloc((NSUB * FEAT + NSUB) * 4);
    float* scnt   = ssum + NSUB * FEAT;
    float* wsub   = (float*)alloc(NSUB * 4);
    float* as1    = (float*)alloc((size_t)N_NODES * 4 * 4);
    float* ad1    = (float*)alloc((size_t)N_NODES * 4 * 4);
    float* as2    = (float*)alloc((size_t)N_NODES * 4);
    float* ad2    = (float*)alloc((size_t)N_NODES * 4);
    int*   counts = (int*)alloc((size_t)N_NODES * 2 * 4);
    int*   cursor = counts + N_NODES;
    int*   offs   = (int*)alloc((size_t)(N_NODES + 1) * 4);
    int*   bsum   = (int*)alloc(256 * 4);
    int*   esrc   = (int*)alloc((size_t)E_RAWN * 4);
    float* gpool  = (float*)alloc((size_t)NGRAPH * HID * 4);
    float* h1     = (float*)alloc((size_t)N_NODES * 256 * 4);
    float* hact   = (float*)alloc((size_t)N_NODES * 256 * 4);
    float* h2     = h1;     // overlay: h1 dead after k_gat1
    float* rbuf   = hact;   // overlay: hact dead after k_gemm2

    (void)hipMemsetAsync(ssum,   0, (NSUB * FEAT + NSUB) * 4, stream);
    (void)hipMemsetAsync(counts, 0, (size_t)N_NODES * 2 * 4, stream);

    k_subst_accum<<<256, 256, 0, stream>>>(x, ssum, scnt);
    k_subst_mlp<<<1, 32, 0, stream>>>(ssum, scnt, w_sa1, b_sa1, w_sa2, b_sa2, wsub);
    k_gemm1<<<(N_NODES + 63) / 64, 256, 0, stream>>>(x, wsub, W1, att_s1, att_d1, h1, as1, ad1);

    k_count<<<(E_RAWN + 255) / 256, 256, 0, stream>>>(e_dst, counts);
    k_scan1<<<NB_SCAN, 256, 0, stream>>>(counts, offs, bsum);
    k_scan2<<<1, 256, 0, stream>>>(bsum, NB_SCAN);
    k_scan3<<<NB_SCAN, 256, 0, stream>>>(offs, bsum);
    k_scatter<<<(E_RAWN + 255) / 256, 256, 0, stream>>>(e_src, e_dst, offs, cursor, esrc);

    k_gat1<<<(N_NODES + 3) / 4, 256, 0, stream>>>(h1, as1, ad1, offs, esrc, b1, hact);
    k_gemm2<<<(N_NODES + 31) / 32, 256, 0, stream>>>(hact, W2, att_s2, att_d2, h2, as2, ad2);
    k_gat2<<<(N_NODES + 3) / 4, 256, 0, stream>>>(h2, as2, ad2, offs, esrc, rbuf);
    k_pool<<<NGRAPH, 256, 0, stream>>>(rbuf, batch, b2, gpool);
    k_head<<<1, 128, 0, stream>>>(gpool, Wp1, bp1, Wp2, bp2, out);
}

// Round 3
// 454.151 us; speedup vs baseline: 1.2200x; 1.1564x over previous
//
#include <hip/hip_runtime.h>
#include <math.h>

#define N_NODES 50000
#define E_RAWN  600000
#define FEAT    64
#define HID     64
#define HEADS   4
#define NSUB    32
#define NGRAPH  128
#define NB_SCAN ((N_NODES + 255) / 256)   // 196
#define G2_NODES 128

__device__ __forceinline__ float leaky02(float v) { return v >= 0.f ? v : 0.2f * v; }
__device__ __forceinline__ float elu1(float v)    { return v > 0.f ? v : expm1f(v); }

// ---------- Phase A: substructure mean + attention MLP + softmax ----------
__global__ void k_subst_accum(const float* __restrict__ x,
                              float* __restrict__ ssum, float* __restrict__ scnt) {
    __shared__ float lsum[NSUB * FEAT];
    __shared__ float lcnt[NSUB];
    int tid = threadIdx.x;
    for (int i = tid; i < NSUB * FEAT; i += blockDim.x) lsum[i] = 0.f;
    if (tid < NSUB) lcnt[tid] = 0.f;
    __syncthreads();
    const int total = N_NODES * FEAT;
    for (int idx = blockIdx.x * blockDim.x + tid; idx < total; idx += gridDim.x * blockDim.x) {
        int node = idx >> 6, f = idx & 63;
        int sid = (int)x[node * FEAT + 5];
        atomicAdd(&lsum[sid * FEAT + f], x[idx]);
        if (f == 0) atomicAdd(&lcnt[sid], 1.f);
    }
    __syncthreads();
    for (int i = tid; i < NSUB * FEAT; i += blockDim.x) atomicAdd(&ssum[i], lsum[i]);
    if (tid < NSUB) atomicAdd(&scnt[tid], lcnt[tid]);
}

__global__ void k_subst_mlp(const float* __restrict__ ssum, const float* __restrict__ scnt,
                            const float* __restrict__ w_sa1, const float* __restrict__ b_sa1,
                            const float* __restrict__ w_sa2, const float* __restrict__ b_sa2,
                            float* __restrict__ wsub) {
    __shared__ float logits[NSUB];
    int s = threadIdx.x;   // 0..31
    float cnt = fmaxf(scnt[s], 1.f);
    float sm[FEAT];
    for (int k = 0; k < FEAT; k++) sm[k] = ssum[s * FEAT + k] / cnt;
    float logit = b_sa2[0];
    for (int j = 0; j < 32; j++) {
        float hj = b_sa1[j];
        for (int k = 0; k < FEAT; k++) hj += sm[k] * w_sa1[k * 32 + j];
        hj = leaky02(hj);
        logit += hj * w_sa2[j];
    }
    logits[s] = logit;
    __syncthreads();
    float m = -1e30f;
    for (int i = 0; i < NSUB; i++) m = fmaxf(m, logits[i]);
    float dsum = 0.f;
    for (int i = 0; i < NSUB; i++) dsum += expf(logits[i] - m);
    wsub[s] = expf(logits[s] - m) / dsum;
}

// ---------- Phase B: h1 = [x, atom_w] @ W1 (register-tiled, LDS x-tile) ----------
__global__ __launch_bounds__(256) void k_gemm1(const float* __restrict__ x,
                                               const float* __restrict__ wsub,
                                               const float* __restrict__ W1,
                                               const float* __restrict__ att_s1,
                                               const float* __restrict__ att_d1,
                                               float* __restrict__ h1,
                                               float* __restrict__ as1, float* __restrict__ ad1) {
    __shared__ float xs[65][68];
    int t = threadIdx.x;
    int gbase = blockIdx.x * 64;
    for (int idx = t; idx < 64 * 64; idx += 256) {
        int n = idx >> 6, f = idx & 63;
        int g = gbase + n;
        xs[f][n] = (g < N_NODES) ? x[(size_t)g * FEAT + f] : 0.f;
    }
    __syncthreads();
    if (t < 64) {
        int sid = (int)xs[5][t];
        xs[64][t] = wsub[sid & (NSUB - 1)];
    }
    __syncthreads();

    int m = t & 31, q = t >> 5;
    int c0 = m * 8, q8 = q * 8;
    float accs[64];
    #pragma unroll
    for (int i = 0; i < 64; ++i) accs[i] = 0.f;

    for (int k = 0; k < 65; ++k) {
        float4 wa = *(const float4*)(W1 + (size_t)k * 256 + c0);
        float4 wb = *(const float4*)(W1 + (size_t)k * 256 + c0 + 4);
        float4 xa = *(const float4*)(&xs[k][q8]);
        float4 xb = *(const float4*)(&xs[k][q8 + 4]);
        float wv[8] = {wa.x, wa.y, wa.z, wa.w, wb.x, wb.y, wb.z, wb.w};
        float xv[8] = {xa.x, xa.y, xa.z, xa.w, xb.x, xb.y, xb.z, xb.w};
        #pragma unroll
        for (int c = 0; c < 8; ++c)
            #pragma unroll
            for (int j = 0; j < 8; ++j)
                accs[c * 8 + j] += wv[c] * xv[j];
    }

    float atts[8], attd[8];
    #pragma unroll
    for (int c = 0; c < 8; ++c) { atts[c] = att_s1[c0 + c]; attd[c] = att_d1[c0 + c]; }
    int h = m >> 3;
    #pragma unroll
    for (int j = 0; j < 8; ++j) {
        int node = gbase + q8 + j;
        float ps = 0.f, pd = 0.f;
        #pragma unroll
        for (int c = 0; c < 8; ++c) { ps += accs[c * 8 + j] * atts[c]; pd += accs[c * 8 + j] * attd[c]; }
        ps += __shfl_xor(ps, 1, 64); pd += __shfl_xor(pd, 1, 64);
        ps += __shfl_xor(ps, 2, 64); pd += __shfl_xor(pd, 2, 64);
        ps += __shfl_xor(ps, 4, 64); pd += __shfl_xor(pd, 4, 64);
        if (node < N_NODES) {
            float4 lo = make_float4(accs[0 * 8 + j], accs[1 * 8 + j], accs[2 * 8 + j], accs[3 * 8 + j]);
            float4 hi = make_float4(accs[4 * 8 + j], accs[5 * 8 + j], accs[6 * 8 + j], accs[7 * 8 + j]);
            *(float4*)(h1 + (size_t)node * 256 + c0) = lo;
            *(float4*)(h1 + (size_t)node * 256 + c0 + 4) = hi;
            if ((m & 7) == 0) { as1[node * 4 + h] = ps; ad1[node * 4 + h] = pd; }
        }
    }
}

// ---------- CSR build (by dst) ----------
__global__ void k_count(const int* __restrict__ dst, int* __restrict__ cnt) {
    int e = blockIdx.x * blockDim.x + threadIdx.x;
    if (e < E_RAWN) atomicAdd(&cnt[dst[e]], 1);
}

__global__ void k_scan1(const int* __restrict__ cnt, int* __restrict__ offs, int* __restrict__ bsum) {
    __shared__ int sd[256];
    int tid = threadIdx.x;
    int i = blockIdx.x * 256 + tid;
    int v = (i < N_NODES) ? cnt[i] : 0;
    sd[tid] = v;
    for (int off = 1; off < 256; off <<= 1) {
        __syncthreads();
        int tv = (tid >= off) ? sd[tid - off] : 0;
        __syncthreads();
        sd[tid] += tv;
    }
    __syncthreads();
    if (i < N_NODES) offs[i] = sd[tid] - v;
    if (tid == 255) bsum[blockIdx.x] = sd[255];
}

__global__ void k_scan2(int* __restrict__ bsum, int nb) {
    __shared__ int sd[256];
    int tid = threadIdx.x;
    int v = (tid < nb) ? bsum[tid] : 0;
    sd[tid] = v;
    for (int off = 1; off < 256; off <<= 1) {
        __syncthreads();
        int tv = (tid >= off) ? sd[tid - off] : 0;
        __syncthreads();
        sd[tid] += tv;
    }
    __syncthreads();
    if (tid < nb) bsum[tid] = sd[tid] - v;
}

__global__ void k_scan3(int* __restrict__ offs, const int* __restrict__ bsum) {
    int i = blockIdx.x * 256 + threadIdx.x;
    if (i < N_NODES) offs[i] += bsum[blockIdx.x];
    if (blockIdx.x == 0 && threadIdx.x == 0) offs[N_NODES] = E_RAWN;
}

__global__ void k_scatter(const int* __restrict__ src, const int* __restrict__ dst,
                          const int* __restrict__ offs, int* __restrict__ cur,
                          int* __restrict__ esrc) {
    int e = blockIdx.x * blockDim.x + threadIdx.x;
    if (e < E_RAWN) {
        int d = dst[e];
        int pos = offs[d] + atomicAdd(&cur[d], 1);
        esrc[pos] = src[e];
    }
}

// ---------- Phase D: GAT layer 1 aggregation, two-pass (no max-sub) ----------
__global__ __launch_bounds__(256) void k_gat1(const float* __restrict__ h1,
                                              const float* __restrict__ as1,
                                              const float* __restrict__ ad1,
                                              const int* __restrict__ offs,
                                              const int* __restrict__ esrc,
                                              const float* __restrict__ b1,
                                              float* __restrict__ hact) {
    int wave = threadIdx.x >> 6, lane = threadIdx.x & 63;
    int i = blockIdx.x * 4 + wave;
    if (i >= N_NODES) return;
    int beg = offs[i], end = offs[i + 1];
    int hh = lane & 3;
    float adv_hh = ad1[i * 4 + hh];
    float dl = 0.f;
    for (int p0 = beg; p0 < end; p0 += 16) {
        int p = p0 + (lane >> 2);
        if (p < end) {
            int s = esrc[p];
            dl += expf(leaky02(as1[s * 4 + hh] + adv_hh));
        }
    }
    dl += __shfl_xor(dl, 4, 64);
    dl += __shfl_xor(dl, 8, 64);
    dl += __shfl_xor(dl, 16, 64);
    dl += __shfl_xor(dl, 32, 64);
    dl += expf(leaky02(as1[i * 4 + hh] + adv_hh));   // self loop
    int h = lane >> 4;
    float d = __shfl(dl, h, 4);
    float inv = 1.f / (d + 1e-16f);
    float adv = ad1[i * 4 + h];
    float w0 = expf(leaky02(as1[i * 4 + h] + adv));
    float4 hv = *(const float4*)(h1 + (size_t)i * 256 + lane * 4);
    float4 acc = make_float4(w0 * hv.x, w0 * hv.y, w0 * hv.z, w0 * hv.w);
    int p = beg;
    for (; p + 1 < end; p += 2) {
        int s0 = esrc[p], s1 = esrc[p + 1];
        float w1_ = expf(leaky02(as1[s0 * 4 + h] + adv));
        float w2_ = expf(leaky02(as1[s1 * 4 + h] + adv));
        float4 ha = *(const float4*)(h1 + (size_t)s0 * 256 + lane * 4);
        float4 hb = *(const float4*)(h1 + (size_t)s1 * 256 + lane * 4);
        acc.x += w1_ * ha.x + w2_ * hb.x;
        acc.y += w1_ * ha.y + w2_ * hb.y;
        acc.z += w1_ * ha.z + w2_ * hb.z;
        acc.w += w1_ * ha.w + w2_ * hb.w;
    }
    if (p < end) {
        int s0 = esrc[p];
        float w1_ = expf(leaky02(as1[s0 * 4 + h] + adv));
        float4 ha = *(const float4*)(h1 + (size_t)s0 * 256 + lane * 4);
        acc.x += w1_ * ha.x; acc.y += w1_ * ha.y; acc.z += w1_ * ha.z; acc.w += w1_ * ha.w;
    }
    float4 bb = *(const float4*)(b1 + lane * 4);
    float4 r;
    r.x = elu1(acc.x * inv + bb.x);
    r.y = elu1(acc.y * inv + bb.y);
    r.z = elu1(acc.z * inv + bb.z);
    r.w = elu1(acc.w * inv + bb.w);
    *(float4*)(hact + (size_t)i * 256 + lane * 4) = r;
}

// ---------- Phase E: h2 = hact @ W2 (register-tiled, K-chunked LDS) ----------
// Block: 256 threads, 128 nodes. Thread: m = t&7 owns cols m*8..m*8+7,
// q = t>>3 owns nodes q*4..q*4+3. accs[8 cols][4 nodes]. K in 4 chunks of 64.
__global__ __launch_bounds__(256) void k_gemm2(const float* __restrict__ hact,
                                               const float* __restrict__ W2,
                                               const float* __restrict__ att_s2,
                                               const float* __restrict__ att_d2,
                                               float* __restrict__ h2,
                                               float* __restrict__ as2, float* __restrict__ ad2) {
    __shared__ float hs[G2_NODES][68];   // one 64-k chunk, [node][k], 272B rows
    int t = threadIdx.x;
    int gbase = blockIdx.x * G2_NODES;
    int m = t & 7, q = t >> 3;
    int c0 = m * 8, n0 = q * 4;
    float accs[32];                       // [col c][node j] = accs[c*4+j]
    #pragma unroll
    for (int i = 0; i < 32; ++i) accs[i] = 0.f;

    int sn = t >> 4;      // staging node (stride 16)
    int skq = t & 15;     // staging k-quad

    for (int kc = 0; kc < 4; ++kc) {
        __syncthreads();
        #pragma unroll
        for (int r = 0; r < 8; ++r) {
            int n = sn + r * 16;
            int g = gbase + n;
            float4 v = (g < N_NODES)
                ? *(const float4*)(hact + (size_t)g * 256 + kc * 64 + skq * 4)
                : make_float4(0.f, 0.f, 0.f, 0.f);
            *(float4*)(&hs[n][skq * 4]) = v;
        }
        __syncthreads();
        const float* Wc = W2 + (size_t)kc * 64 * 64;
        for (int kk = 0; kk < 16; ++kk) {
            float4 xv0 = *(const float4*)(&hs[n0 + 0][kk * 4]);
            float4 xv1 = *(const float4*)(&hs[n0 + 1][kk * 4]);
            float4 xv2 = *(const float4*)(&hs[n0 + 2][kk * 4]);
            float4 xv3 = *(const float4*)(&hs[n0 + 3][kk * 4]);
            const float* x0 = (const float*)&xv0;
            const float* x1 = (const float*)&xv1;
            const float* x2 = (const float*)&xv2;
            const float* x3 = (const float*)&xv3;
            #pragma unroll
            for (int jj = 0; jj < 4; ++jj) {
                int k = kk * 4 + jj;
                float4 wa = *(const float4*)(Wc + (size_t)k * 64 + c0);
                float4 wb = *(const float4*)(Wc + (size_t)k * 64 + c0 + 4);
                float wv[8] = {wa.x, wa.y, wa.z, wa.w, wb.x, wb.y, wb.z, wb.w};
                float xj[4] = {x0[jj], x1[jj], x2[jj], x3[jj]};
                #pragma unroll
                for (int c = 0; c < 8; ++c)
                    #pragma unroll
                    for (int j = 0; j < 4; ++j)
                        accs[c * 4 + j] += wv[c] * xj[j];
            }
        }
    }

    float atts[8], attd[8];
    #pragma unroll
    for (int c = 0; c < 8; ++c) { atts[c] = att_s2[c0 + c]; attd[c] = att_d2[c0 + c]; }
    #pragma unroll
    for (int j = 0; j < 4; ++j) {
        int node = gbase + n0 + j;
        float ps = 0.f, pd = 0.f;
        #pragma unroll
        for (int c = 0; c < 8; ++c) { ps += accs[c * 4 + j] * atts[c]; pd += accs[c * 4 + j] * attd[c]; }
        ps += __shfl_xor(ps, 1, 64); pd += __shfl_xor(pd, 1, 64);
        ps += __shfl_xor(ps, 2, 64); pd += __shfl_xor(pd, 2, 64);
        ps += __shfl_xor(ps, 4, 64); pd += __shfl_xor(pd, 4, 64);
        if (node < N_NODES) {
            *(float4*)(h2 + (size_t)node * 64 + c0) =
                make_float4(accs[0 * 4 + j], accs[1 * 4 + j], accs[2 * 4 + j], accs[3 * 4 + j]);
            *(float4*)(h2 + (size_t)node * 64 + c0 + 4) =
                make_float4(accs[4 * 4 + j], accs[5 * 4 + j], accs[6 * 4 + j], accs[7 * 4 + j]);
            if (m == 0) { as2[node] = ps; ad2[node] = pd; }
        }
    }
}

// ---------- Phase F: GAT layer 2 aggregation, two-pass (no max-sub), no bias ----------
__global__ __launch_bounds__(256) void k_gat2(const float* __restrict__ h2,
                                              const float* __restrict__ as2,
                                              const float* __restrict__ ad2,
                                              const int* __restrict__ offs,
                                              const int* __restrict__ esrc,
                                              float* __restrict__ rbuf) {
    int wave = threadIdx.x >> 6, lane = threadIdx.x & 63;
    int i = blockIdx.x * 4 + wave;
    if (i >= N_NODES) return;
    int beg = offs[i], end = offs[i + 1];
    float adv = ad2[i];
    float e0 = leaky02(as2[i] + adv);
    float dl = 0.f;
    for (int p0 = beg; p0 < end; p0 += 64) {
        int p = p0 + lane;
        if (p < end) dl += expf(leaky02(as2[esrc[p]] + adv));
    }
    dl += __shfl_xor(dl, 1, 64);
    dl += __shfl_xor(dl, 2, 64);
    dl += __shfl_xor(dl, 4, 64);
    dl += __shfl_xor(dl, 8, 64);
    dl += __shfl_xor(dl, 16, 64);
    dl += __shfl_xor(dl, 32, 64);
    float w0 = expf(e0);
    float d = dl + w0;
    float inv = 1.f / (d + 1e-16f);
    float acc = w0 * h2[(size_t)i * 64 + lane];
    int p = beg;
    for (; p + 1 < end; p += 2) {
        int s0 = esrc[p], s1 = esrc[p + 1];
        float wA = expf(leaky02(as2[s0] + adv));
        float wB = expf(leaky02(as2[s1] + adv));
        float hA = h2[(size_t)s0 * 64 + lane];
        float hB = h2[(size_t)s1 * 64 + lane];
        acc += wA * hA + wB * hB;
    }
    if (p < end) {
        int s0 = esrc[p];
        acc += expf(leaky02(as2[s0] + adv)) * h2[(size_t)s0 * 64 + lane];
    }
    rbuf[(size_t)i * 64 + lane] = acc * inv;
}

// ---------- Phase G: pool per graph (batch sorted, binary search ranges) ----------
__device__ __forceinline__ int lower_bound_i(const int* a, int n, int v) {
    int lo = 0, hi = n;
    while (lo < hi) { int mid = (lo + hi) >> 1; if (a[mid] < v) lo = mid + 1; else hi = mid; }
    return lo;
}

__global__ void k_pool(const float* __restrict__ rbuf, const int* __restrict__ batch,
                       const float* __restrict__ b2, float* __restrict__ g) {
    __shared__ float red[4][64];
    int b = blockIdx.x;
    int lo = lower_bound_i(batch, N_NODES, b);
    int hi = lower_bound_i(batch, N_NODES, b + 1);
    int c = threadIdx.x & 63, rg = threadIdx.x >> 6;
    float s = 0.f;
    for (int r = lo + rg; r < hi; r += 4) s += rbuf[(size_t)r * 64 + c];
    red[rg][c] = s;
    __syncthreads();
    if (rg == 0) {
        float tot = red[0][c] + red[1][c] + red[2][c] + red[3][c] + (float)(hi - lo) * b2[c];
        g[(size_t)b * 64 + c] = tot;
    }
}

// ---------- Phase H: prediction head ----------
__global__ void k_head(const float* __restrict__ g,
                       const float* __restrict__ Wp1, const float* __restrict__ bp1,
                       const float* __restrict__ Wp2, const float* __restrict__ bp2,
                       float* __restrict__ out) {
    int t = threadIdx.x;
    if (t >= NGRAPH) return;
    float acc = bp2[0];
    for (int j = 0; j < 32; j++) {
        float hj = bp1[j];
        for (int k = 0; k < 64; k++) hj += g[(size_t)t * 64 + k] * Wp1[k * 32 + j];
        hj = elu1(hj);
        acc += hj * Wp2[j];
    }
    out[t] = acc;
}

extern "C" void kernel_launch(void* const* d_in, const int* in_sizes, int n_in,
                              void* d_out, int out_size, void* d_ws, size_t ws_size,
                              hipStream_t stream) {
    const float* x      = (const float*)d_in[0];
    const int*   edge   = (const int*)d_in[1];
    const int*   batch  = (const int*)d_in[2];
    const float* w_sa1  = (const float*)d_in[3];
    const float* b_sa1  = (const float*)d_in[4];
    const float* w_sa2  = (const float*)d_in[5];
    const float* b_sa2  = (const float*)d_in[6];
    const float* W1     = (const float*)d_in[7];
    const float* att_s1 = (const float*)d_in[8];
    const float* att_d1 = (const float*)d_in[9];
    const float* b1     = (const float*)d_in[10];
    const float* W2     = (const float*)d_in[11];
    const float* att_s2 = (const float*)d_in[12];
    const float* att_d2 = (const float*)d_in[13];
    const float* b2     = (const float*)d_in[14];
    const float* Wp1    = (const float*)d_in[15];
    const float* bp1    = (const float*)d_in[16];
    const float* Wp2    = (const float*)d_in[17];
    const float* bp2    = (const float*)d_in[18];
    float* out = (float*)d_out;

    const int* e_src = edge;
    const int* e_dst = edge + E_RAWN;

    char* base = (char*)d_ws;
    size_t off = 0;
    auto alloc = [&](size_t bytes) -> void* {
        void* p = base + off;
        off = (off + bytes + 255) & ~(size_t)255;
        return p;
    };
    float* ssum   = (float*)alloc((NSUB * FEAT + NSUB) * 4);
    float* scnt   = ssum + NSUB * FEAT;
    float* wsub   = (float*)alloc(NSUB * 4);
    float* as1    = (float*)alloc((size_t)N_NODES * 4 * 4);
    float* ad1    = (float*)alloc((size_t)N_NODES * 4 * 4);
    float* as2    = (float*)alloc((size_t)N_NODES * 4);
    float* ad2    = (float*)alloc((size_t)N_NODES * 4);
    int*   counts = (int*)alloc((size_t)N_NODES * 2 * 4);
    int*   cursor = counts + N_NODES;
    int*   offs   = (int*)alloc((size_t)(N_NODES + 1) * 4);
    int*   bsum   = (int*)alloc(256 * 4);
    int*   esrc   = (int*)alloc((size_t)E_RAWN * 4);
    float* gpool  = (float*)alloc((size_t)NGRAPH * HID * 4);
    float* h1     = (float*)alloc((size_t)N_NODES * 256 * 4);
    float* hact   = (float*)alloc((size_t)N_NODES * 256 * 4);
    float* h2     = h1;     // overlay: h1 dead after k_gat1
    float* rbuf   = hact;   // overlay: hact dead after k_gemm2

    (void)hipMemsetAsync(ssum,   0, (NSUB * FEAT + NSUB) * 4, stream);
    (void)hipMemsetAsync(counts, 0, (size_t)N_NODES * 2 * 4, stream);

    k_subst_accum<<<256, 256, 0, stream>>>(x, ssum, scnt);
    k_subst_mlp<<<1, 32, 0, stream>>>(ssum, scnt, w_sa1, b_sa1, w_sa2, b_sa2, wsub);
    k_gemm1<<<(N_NODES + 63) / 64, 256, 0, stream>>>(x, wsub, W1, att_s1, att_d1, h1, as1, ad1);

    k_count<<<(E_RAWN + 255) / 256, 256, 0, stream>>>(e_dst, counts);
    k_scan1<<<NB_SCAN, 256, 0, stream>>>(counts, offs, bsum);
    k_scan2<<<1, 256, 0, stream>>>(bsum, NB_SCAN);
    k_scan3<<<NB_SCAN, 256, 0, stream>>>(offs, bsum);
    k_scatter<<<(E_RAWN + 255) / 256, 256, 0, stream>>>(e_src, e_dst, offs, cursor, esrc);

    k_gat1<<<(N_NODES + 3) / 4, 256, 0, stream>>>(h1, as1, ad1, offs, esrc, b1, hact);
    k_gemm2<<<(N_NODES + G2_NODES - 1) / G2_NODES, 256, 0, stream>>>(hact, W2, att_s2, att_d2, h2, as2, ad2);
    k_gat2<<<(N_NODES + 3) / 4, 256, 0, stream>>>(h2, as2, ad2, offs, esrc, rbuf);
    k_pool<<<NGRAPH, 256, 0, stream>>>(rbuf, batch, b2, gpool);
    k_head<<<1, 128, 0, stream>>>(gpool, Wp1, bp1, Wp2, bp2, out);
}

// Round 4
// 409.758 us; speedup vs baseline: 1.3521x; 1.1083x over previous
//
#include <hip/hip_runtime.h>
#include <math.h>

#define N_NODES 50000
#define E_RAWN  600000
#define FEAT    64
#define HID     64
#define HEADS   4
#define NSUB    32
#define NGRAPH  128
#define NB_SCAN ((N_NODES + 255) / 256)   // 196
#define G2_NODES 128

__device__ __forceinline__ float leaky02(float v) { return v >= 0.f ? v : 0.2f * v; }
__device__ __forceinline__ float elu1(float v)    { return v > 0.f ? v : expm1f(v); }

// bf16 pack/unpack (RNE), 2 per uint
__device__ __forceinline__ unsigned bf2pack(float a, float b) {
    unsigned ua = __float_as_uint(a), ub = __float_as_uint(b);
    ua = (ua + 0x7FFFu + ((ua >> 16) & 1u)) >> 16;
    ub = (ub + 0x7FFFu + ((ub >> 16) & 1u)) >> 16;
    return ua | (ub << 16);
}
__device__ __forceinline__ float bflo(unsigned p) { return __uint_as_float(p << 16); }
__device__ __forceinline__ float bfhi(unsigned p) { return __uint_as_float(p & 0xFFFF0000u); }

// ---------- Phase A: substructure mean + attention MLP + softmax ----------
__global__ void k_subst_accum(const float* __restrict__ x,
                              float* __restrict__ ssum, float* __restrict__ scnt) {
    __shared__ float lsum[NSUB * FEAT];
    __shared__ float lcnt[NSUB];
    int tid = threadIdx.x;
    for (int i = tid; i < NSUB * FEAT; i += blockDim.x) lsum[i] = 0.f;
    if (tid < NSUB) lcnt[tid] = 0.f;
    __syncthreads();
    const int total = N_NODES * FEAT;
    for (int idx = blockIdx.x * blockDim.x + tid; idx < total; idx += gridDim.x * blockDim.x) {
        int node = idx >> 6, f = idx & 63;
        int sid = (int)x[node * FEAT + 5];
        atomicAdd(&lsum[sid * FEAT + f], x[idx]);
        if (f == 0) atomicAdd(&lcnt[sid], 1.f);
    }
    __syncthreads();
    for (int i = tid; i < NSUB * FEAT; i += blockDim.x) atomicAdd(&ssum[i], lsum[i]);
    if (tid < NSUB) atomicAdd(&scnt[tid], lcnt[tid]);
}

__global__ void k_subst_mlp(const float* __restrict__ ssum, const float* __restrict__ scnt,
                            const float* __restrict__ w_sa1, const float* __restrict__ b_sa1,
                            const float* __restrict__ w_sa2, const float* __restrict__ b_sa2,
                            float* __restrict__ wsub) {
    __shared__ float logits[NSUB];
    int s = threadIdx.x;   // 0..31
    float cnt = fmaxf(scnt[s], 1.f);
    float sm[FEAT];
    for (int k = 0; k < FEAT; k++) sm[k] = ssum[s * FEAT + k] / cnt;
    float logit = b_sa2[0];
    for (int j = 0; j < 32; j++) {
        float hj = b_sa1[j];
        for (int k = 0; k < FEAT; k++) hj += sm[k] * w_sa1[k * 32 + j];
        hj = leaky02(hj);
        logit += hj * w_sa2[j];
    }
    logits[s] = logit;
    __syncthreads();
    float m = -1e30f;
    for (int i = 0; i < NSUB; i++) m = fmaxf(m, logits[i]);
    float dsum = 0.f;
    for (int i = 0; i < NSUB; i++) dsum += expf(logits[i] - m);
    wsub[s] = expf(logits[s] - m) / dsum;
}

// ---------- Phase B: h1 = [x, atom_w] @ W1 (register-tiled, LDS x-tile) ----------
// h1 stored as bf16 (packed 2/uint, row = 128 uints). as1/ad1 from f32 accs (exact).
__global__ __launch_bounds__(256) void k_gemm1(const float* __restrict__ x,
                                               const float* __restrict__ wsub,
                                               const float* __restrict__ W1,
                                               const float* __restrict__ att_s1,
                                               const float* __restrict__ att_d1,
                                               unsigned* __restrict__ h1b,
                                               float* __restrict__ as1, float* __restrict__ ad1) {
    __shared__ float xs[65][68];
    int t = threadIdx.x;
    int gbase = blockIdx.x * 64;
    for (int idx = t; idx < 64 * 64; idx += 256) {
        int n = idx >> 6, f = idx & 63;
        int g = gbase + n;
        xs[f][n] = (g < N_NODES) ? x[(size_t)g * FEAT + f] : 0.f;
    }
    __syncthreads();
    if (t < 64) {
        int sid = (int)xs[5][t];
        xs[64][t] = wsub[sid & (NSUB - 1)];
    }
    __syncthreads();

    int m = t & 31, q = t >> 5;
    int c0 = m * 8, q8 = q * 8;
    float accs[64];
    #pragma unroll
    for (int i = 0; i < 64; ++i) accs[i] = 0.f;

    for (int k = 0; k < 65; ++k) {
        float4 wa = *(const float4*)(W1 + (size_t)k * 256 + c0);
        float4 wb = *(const float4*)(W1 + (size_t)k * 256 + c0 + 4);
        float4 xa = *(const float4*)(&xs[k][q8]);
        float4 xb = *(const float4*)(&xs[k][q8 + 4]);
        float wv[8] = {wa.x, wa.y, wa.z, wa.w, wb.x, wb.y, wb.z, wb.w};
        float xv[8] = {xa.x, xa.y, xa.z, xa.w, xb.x, xb.y, xb.z, xb.w};
        #pragma unroll
        for (int c = 0; c < 8; ++c)
            #pragma unroll
            for (int j = 0; j < 8; ++j)
                accs[c * 8 + j] += wv[c] * xv[j];
    }

    float atts[8], attd[8];
    #pragma unroll
    for (int c = 0; c < 8; ++c) { atts[c] = att_s1[c0 + c]; attd[c] = att_d1[c0 + c]; }
    int h = m >> 3;
    #pragma unroll
    for (int j = 0; j < 8; ++j) {
        int node = gbase + q8 + j;
        float ps = 0.f, pd = 0.f;
        #pragma unroll
        for (int c = 0; c < 8; ++c) { ps += accs[c * 8 + j] * atts[c]; pd += accs[c * 8 + j] * attd[c]; }
        ps += __shfl_xor(ps, 1, 64); pd += __shfl_xor(pd, 1, 64);
        ps += __shfl_xor(ps, 2, 64); pd += __shfl_xor(pd, 2, 64);
        ps += __shfl_xor(ps, 4, 64); pd += __shfl_xor(pd, 4, 64);
        if (node < N_NODES) {
            uint4 pk;
            pk.x = bf2pack(accs[0 * 8 + j], accs[1 * 8 + j]);
            pk.y = bf2pack(accs[2 * 8 + j], accs[3 * 8 + j]);
            pk.z = bf2pack(accs[4 * 8 + j], accs[5 * 8 + j]);
            pk.w = bf2pack(accs[6 * 8 + j], accs[7 * 8 + j]);
            *(uint4*)(h1b + (size_t)node * 128 + m * 4) = pk;
            if ((m & 7) == 0) { as1[node * 4 + h] = ps; ad1[node * 4 + h] = pd; }
        }
    }
}

// ---------- CSR build (by dst) ----------
__global__ void k_count(const int* __restrict__ dst, int* __restrict__ cnt) {
    int e = blockIdx.x * blockDim.x + threadIdx.x;
    if (e < E_RAWN) atomicAdd(&cnt[dst[e]], 1);
}

__global__ void k_scan1(const int* __restrict__ cnt, int* __restrict__ offs, int* __restrict__ bsum) {
    __shared__ int sd[256];
    int tid = threadIdx.x;
    int i = blockIdx.x * 256 + tid;
    int v = (i < N_NODES) ? cnt[i] : 0;
    sd[tid] = v;
    for (int off = 1; off < 256; off <<= 1) {
        __syncthreads();
        int tv = (tid >= off) ? sd[tid - off] : 0;
        __syncthreads();
        sd[tid] += tv;
    }
    __syncthreads();
    if (i < N_NODES) offs[i] = sd[tid] - v;
    if (tid == 255) bsum[blockIdx.x] = sd[255];
}

__global__ void k_scan2(int* __restrict__ bsum, int nb) {
    __shared__ int sd[256];
    int tid = threadIdx.x;
    int v = (tid < nb) ? bsum[tid] : 0;
    sd[tid] = v;
    for (int off = 1; off < 256; off <<= 1) {
        __syncthreads();
        int tv = (tid >= off) ? sd[tid - off] : 0;
        __syncthreads();
        sd[tid] += tv;
    }
    __syncthreads();
    if (tid < nb) bsum[tid] = sd[tid] - v;
}

__global__ void k_scan3(int* __restrict__ offs, const int* __restrict__ bsum) {
    int i = blockIdx.x * 256 + threadIdx.x;
    if (i < N_NODES) offs[i] += bsum[blockIdx.x];
    if (blockIdx.x == 0 && threadIdx.x == 0) offs[N_NODES] = E_RAWN;
}

__global__ void k_scatter(const int* __restrict__ src, const int* __restrict__ dst,
                          const int* __restrict__ offs, int* __restrict__ cur,
                          int* __restrict__ esrc) {
    int e = blockIdx.x * blockDim.x + threadIdx.x;
    if (e < E_RAWN) {
        int d = dst[e];
        int pos = offs[d] + atomicAdd(&cur[d], 1);
        esrc[pos] = src[e];
    }
}

// ---------- Phase D: GAT layer 1 aggregation, two-pass (no max-sub), bf16 gather ----------
__global__ __launch_bounds__(256) void k_gat1(const unsigned* __restrict__ h1b,
                                              const float* __restrict__ as1,
                                              const float* __restrict__ ad1,
                                              const int* __restrict__ offs,
                                              const int* __restrict__ esrc,
                                              const float* __restrict__ b1,
                                              float* __restrict__ hact) {
    int wave = threadIdx.x >> 6, lane = threadIdx.x & 63;
    int i = blockIdx.x * 4 + wave;
    if (i >= N_NODES) return;
    int beg = offs[i], end = offs[i + 1];
    int hh = lane & 3;
    float adv_hh = ad1[i * 4 + hh];
    float dl = 0.f;
    for (int p0 = beg; p0 < end; p0 += 16) {
        int p = p0 + (lane >> 2);
        if (p < end) {
            int s = esrc[p];
            dl += expf(leaky02(as1[s * 4 + hh] + adv_hh));
        }
    }
    dl += __shfl_xor(dl, 4, 64);
    dl += __shfl_xor(dl, 8, 64);
    dl += __shfl_xor(dl, 16, 64);
    dl += __shfl_xor(dl, 32, 64);
    dl += expf(leaky02(as1[i * 4 + hh] + adv_hh));   // self loop
    int h = lane >> 4;
    float d = __shfl(dl, h, 4);
    float inv = 1.f / (d + 1e-16f);
    float adv = ad1[i * 4 + h];
    float w0 = expf(leaky02(as1[i * 4 + h] + adv));
    uint2 hv = *(const uint2*)(h1b + (size_t)i * 128 + lane * 2);
    float4 acc = make_float4(w0 * bflo(hv.x), w0 * bfhi(hv.x), w0 * bflo(hv.y), w0 * bfhi(hv.y));
    int p = beg;
    for (; p + 1 < end; p += 2) {
        int s0 = esrc[p], s1 = esrc[p + 1];
        float w1_ = expf(leaky02(as1[s0 * 4 + h] + adv));
        float w2_ = expf(leaky02(as1[s1 * 4 + h] + adv));
        uint2 ha = *(const uint2*)(h1b + (size_t)s0 * 128 + lane * 2);
        uint2 hb = *(const uint2*)(h1b + (size_t)s1 * 128 + lane * 2);
        acc.x += w1_ * bflo(ha.x) + w2_ * bflo(hb.x);
        acc.y += w1_ * bfhi(ha.x) + w2_ * bfhi(hb.x);
        acc.z += w1_ * bflo(ha.y) + w2_ * bflo(hb.y);
        acc.w += w1_ * bfhi(ha.y) + w2_ * bfhi(hb.y);
    }
    if (p < end) {
        int s0 = esrc[p];
        float w1_ = expf(leaky02(as1[s0 * 4 + h] + adv));
        uint2 ha = *(const uint2*)(h1b + (size_t)s0 * 128 + lane * 2);
        acc.x += w1_ * bflo(ha.x);
        acc.y += w1_ * bfhi(ha.x);
        acc.z += w1_ * bflo(ha.y);
        acc.w += w1_ * bfhi(ha.y);
    }
    float4 bb = *(const float4*)(b1 + lane * 4);
    float4 r;
    r.x = elu1(acc.x * inv + bb.x);
    r.y = elu1(acc.y * inv + bb.y);
    r.z = elu1(acc.z * inv + bb.z);
    r.w = elu1(acc.w * inv + bb.w);
    *(float4*)(hact + (size_t)i * 256 + lane * 4) = r;
}

// ---------- Phase E: h2 = hact @ W2 (register-tiled, K-chunked LDS) ----------
__global__ __launch_bounds__(256) void k_gemm2(const float* __restrict__ hact,
                                               const float* __restrict__ W2,
                                               const float* __restrict__ att_s2,
                                               const float* __restrict__ att_d2,
                                               float* __restrict__ h2,
                                               float* __restrict__ as2, float* __restrict__ ad2) {
    __shared__ float hs[G2_NODES][68];   // one 64-k chunk, [node][k], 272B rows
    int t = threadIdx.x;
    int gbase = blockIdx.x * G2_NODES;
    int m = t & 7, q = t >> 3;
    int c0 = m * 8, n0 = q * 4;
    float accs[32];                       // [col c][node j] = accs[c*4+j]
    #pragma unroll
    for (int i = 0; i < 32; ++i) accs[i] = 0.f;

    int sn = t >> 4;      // staging node (stride 16)
    int skq = t & 15;     // staging k-quad

    for (int kc = 0; kc < 4; ++kc) {
        __syncthreads();
        #pragma unroll
        for (int r = 0; r < 8; ++r) {
            int n = sn + r * 16;
            int g = gbase + n;
            float4 v = (g < N_NODES)
                ? *(const float4*)(hact + (size_t)g * 256 + kc * 64 + skq * 4)
                : make_float4(0.f, 0.f, 0.f, 0.f);
            *(float4*)(&hs[n][skq * 4]) = v;
        }
        __syncthreads();
        const float* Wc = W2 + (size_t)kc * 64 * 64;
        for (int kk = 0; kk < 16; ++kk) {
            float4 xv0 = *(const float4*)(&hs[n0 + 0][kk * 4]);
            float4 xv1 = *(const float4*)(&hs[n0 + 1][kk * 4]);
            float4 xv2 = *(const float4*)(&hs[n0 + 2][kk * 4]);
            float4 xv3 = *(const float4*)(&hs[n0 + 3][kk * 4]);
            const float* x0 = (const float*)&xv0;
            const float* x1 = (const float*)&xv1;
            const float* x2 = (const float*)&xv2;
            const float* x3 = (const float*)&xv3;
            #pragma unroll
            for (int jj = 0; jj < 4; ++jj) {
                int k = kk * 4 + jj;
                float4 wa = *(const float4*)(Wc + (size_t)k * 64 + c0);
                float4 wb = *(const float4*)(Wc + (size_t)k * 64 + c0 + 4);
                float wv[8] = {wa.x, wa.y, wa.z, wa.w, wb.x, wb.y, wb.z, wb.w};
                float xj[4] = {x0[jj], x1[jj], x2[jj], x3[jj]};
                #pragma unroll
                for (int c = 0; c < 8; ++c)
                    #pragma unroll
                    for (int j = 0; j < 4; ++j)
                        accs[c * 4 + j] += wv[c] * xj[j];
            }
        }
    }

    float atts[8], attd[8];
    #pragma unroll
    for (int c = 0; c < 8; ++c) { atts[c] = att_s2[c0 + c]; attd[c] = att_d2[c0 + c]; }
    #pragma unroll
    for (int j = 0; j < 4; ++j) {
        int node = gbase + n0 + j;
        float ps = 0.f, pd = 0.f;
        #pragma unroll
        for (int c = 0; c < 8; ++c) { ps += accs[c * 4 + j] * atts[c]; pd += accs[c * 4 + j] * attd[c]; }
        ps += __shfl_xor(ps, 1, 64); pd += __shfl_xor(pd, 1, 64);
        ps += __shfl_xor(ps, 2, 64); pd += __shfl_xor(pd, 2, 64);
        ps += __shfl_xor(ps, 4, 64); pd += __shfl_xor(pd, 4, 64);
        if (node < N_NODES) {
            *(float4*)(h2 + (size_t)node * 64 + c0) =
                make_float4(accs[0 * 4 + j], accs[1 * 4 + j], accs[2 * 4 + j], accs[3 * 4 + j]);
            *(float4*)(h2 + (size_t)node * 64 + c0 + 4) =
                make_float4(accs[4 * 4 + j], accs[5 * 4 + j], accs[6 * 4 + j], accs[7 * 4 + j]);
            if (m == 0) { as2[node] = ps; ad2[node] = pd; }
        }
    }
}

// ---------- Phase F: GAT layer 2 aggregation, two-pass (no max-sub), no bias ----------
__global__ __launch_bounds__(256) void k_gat2(const float* __restrict__ h2,
                                              const float* __restrict__ as2,
                                              const float* __restrict__ ad2,
                                              const int* __restrict__ offs,
                                              const int* __restrict__ esrc,
                                              float* __restrict__ rbuf) {
    int wave = threadIdx.x >> 6, lane = threadIdx.x & 63;
    int i = blockIdx.x * 4 + wave;
    if (i >= N_NODES) return;
    int beg = offs[i], end = offs[i + 1];
    float adv = ad2[i];
    float e0 = leaky02(as2[i] + adv);
    float dl = 0.f;
    for (int p0 = beg; p0 < end; p0 += 64) {
        int p = p0 + lane;
        if (p < end) dl += expf(leaky02(as2[esrc[p]] + adv));
    }
    dl += __shfl_xor(dl, 1, 64);
    dl += __shfl_xor(dl, 2, 64);
    dl += __shfl_xor(dl, 4, 64);
    dl += __shfl_xor(dl, 8, 64);
    dl += __shfl_xor(dl, 16, 64);
    dl += __shfl_xor(dl, 32, 64);
    float w0 = expf(e0);
    float d = dl + w0;
    float inv = 1.f / (d + 1e-16f);
    float acc = w0 * h2[(size_t)i * 64 + lane];
    int p = beg;
    for (; p + 1 < end; p += 2) {
        int s0 = esrc[p], s1 = esrc[p + 1];
        float wA = expf(leaky02(as2[s0] + adv));
        float wB = expf(leaky02(as2[s1] + adv));
        float hA = h2[(size_t)s0 * 64 + lane];
        float hB = h2[(size_t)s1 * 64 + lane];
        acc += wA * hA + wB * hB;
    }
    if (p < end) {
        int s0 = esrc[p];
        acc += expf(leaky02(as2[s0] + adv)) * h2[(size_t)s0 * 64 + lane];
    }
    rbuf[(size_t)i * 64 + lane] = acc * inv;
}

// ---------- Phase G: pool per graph (batch sorted, binary search ranges) ----------
__device__ __forceinline__ int lower_bound_i(const int* a, int n, int v) {
    int lo = 0, hi = n;
    while (lo < hi) { int mid = (lo + hi) >> 1; if (a[mid] < v) lo = mid + 1; else hi = mid; }
    return lo;
}

__global__ void k_pool(const float* __restrict__ rbuf, const int* __restrict__ batch,
                       const float* __restrict__ b2, float* __restrict__ g) {
    __shared__ float red[4][64];
    int b = blockIdx.x;
    int lo = lower_bound_i(batch, N_NODES, b);
    int hi = lower_bound_i(batch, N_NODES, b + 1);
    int c = threadIdx.x & 63, rg = threadIdx.x >> 6;
    float s = 0.f;
    for (int r = lo + rg; r < hi; r += 4) s += rbuf[(size_t)r * 64 + c];
    red[rg][c] = s;
    __syncthreads();
    if (rg == 0) {
        float tot = red[0][c] + red[1][c] + red[2][c] + red[3][c] + (float)(hi - lo) * b2[c];
        g[(size_t)b * 64 + c] = tot;
    }
}

// ---------- Phase H: prediction head ----------
__global__ void k_head(const float* __restrict__ g,
                       const float* __restrict__ Wp1, const float* __restrict__ bp1,
                       const float* __restrict__ Wp2, const float* __restrict__ bp2,
                       float* __restrict__ out) {
    int t = threadIdx.x;
    if (t >= NGRAPH) return;
    float acc = bp2[0];
    for (int j = 0; j < 32; j++) {
        float hj = bp1[j];
        for (int k = 0; k < 64; k++) hj += g[(size_t)t * 64 + k] * Wp1[k * 32 + j];
        hj = elu1(hj);
        acc += hj * Wp2[j];
    }
    out[t] = acc;
}

extern "C" void kernel_launch(void* const* d_in, const int* in_sizes, int n_in,
                              void* d_out, int out_size, void* d_ws, size_t ws_size,
                              hipStream_t stream) {
    const float* x      = (const float*)d_in[0];
    const int*   edge   = (const int*)d_in[1];
    const int*   batch  = (const int*)d_in[2];
    const float* w_sa1  = (const float*)d_in[3];
    const float* b_sa1  = (const float*)d_in[4];
    const float* w_sa2  = (const float*)d_in[5];
    const float* b_sa2  = (const float*)d_in[6];
    const float* W1     = (const float*)d_in[7];
    const float* att_s1 = (const float*)d_in[8];
    const float* att_d1 = (const float*)d_in[9];
    const float* b1     = (const float*)d_in[10];
    const float* W2     = (const float*)d_in[11];
    const float* att_s2 = (const float*)d_in[12];
    const float* att_d2 = (const float*)d_in[13];
    const float* b2     = (const float*)d_in[14];
    const float* Wp1    = (const float*)d_in[15];
    const float* bp1    = (const float*)d_in[16];
    const float* Wp2    = (const float*)d_in[17];
    const float* bp2    = (const float*)d_in[18];
    float* out = (float*)d_out;

    const int* e_src = edge;
    const int* e_dst = edge + E_RAWN;

    char* base = (char*)d_ws;
    size_t off = 0;
    auto alloc = [&](size_t bytes) -> void* {
        void* p = base + off;
        off = (off + bytes + 255) & ~(size_t)255;
        return p;
    };
    float* ssum   = (float*)alloc((NSUB * FEAT + NSUB) * 4);
    float* scnt   = ssum + NSUB * FEAT;
    float* wsub   = (float*)alloc(NSUB * 4);
    float* as1    = (float*)alloc((size_t)N_NODES * 4 * 4);
    float* ad1    = (float*)alloc((size_t)N_NODES * 4 * 4);
    float* as2    = (float*)alloc((size_t)N_NODES * 4);
    float* ad2    = (float*)alloc((size_t)N_NODES * 4);
    int*   counts = (int*)alloc((size_t)N_NODES * 2 * 4);
    int*   cursor = counts + N_NODES;
    int*   offs   = (int*)alloc((size_t)(N_NODES + 1) * 4);
    int*   bsum   = (int*)alloc(256 * 4);
    int*   esrc   = (int*)alloc((size_t)E_RAWN * 4);
    float* gpool  = (float*)alloc((size_t)NGRAPH * HID * 4);
    unsigned* h1b = (unsigned*)alloc((size_t)N_NODES * 128 * 4);   // bf16-packed h1
    float* hact   = (float*)alloc((size_t)N_NODES * 256 * 4);
    float* h2     = (float*)alloc((size_t)N_NODES * 64 * 4);
    float* rbuf   = hact;   // overlay: hact dead after k_gemm2

    (void)hipMemsetAsync(ssum,   0, (NSUB * FEAT + NSUB) * 4, stream);
    (void)hipMemsetAsync(counts, 0, (size_t)N_NODES * 2 * 4, stream);

    k_subst_accum<<<256, 256, 0, stream>>>(x, ssum, scnt);
    k_subst_mlp<<<1, 32, 0, stream>>>(ssum, scnt, w_sa1, b_sa1, w_sa2, b_sa2, wsub);
    k_gemm1<<<(N_NODES + 63) / 64, 256, 0, stream>>>(x, wsub, W1, att_s1, att_d1, h1b, as1, ad1);

    k_count<<<(E_RAWN + 255) / 256, 256, 0, stream>>>(e_dst, counts);
    k_scan1<<<NB_SCAN, 256, 0, stream>>>(counts, offs, bsum);
    k_scan2<<<1, 256, 0, stream>>>(bsum, NB_SCAN);
    k_scan3<<<NB_SCAN, 256, 0, stream>>>(offs, bsum);
    k_scatter<<<(E_RAWN + 255) / 256, 256, 0, stream>>>(e_src, e_dst, offs, cursor, esrc);

    k_gat1<<<(N_NODES + 3) / 4, 256, 0, stream>>>(h1b, as1, ad1, offs, esrc, b1, hact);
    k_gemm2<<<(N_NODES + G2_NODES - 1) / G2_NODES, 256, 0, stream>>>(hact, W2, att_s2, att_d2, h2, as2, ad2);
    k_gat2<<<(N_NODES + 3) / 4, 256, 0, stream>>>(h2, as2, ad2, offs, esrc, rbuf);
    k_pool<<<NGRAPH, 256, 0, stream>>>(rbuf, batch, b2, gpool);
    k_head<<<1, 128, 0, stream>>>(gpool, Wp1, bp1, Wp2, bp2, out);
}

// Round 5
// 375.634 us; speedup vs baseline: 1.4750x; 1.0908x over previous
//
#include <hip/hip_runtime.h>
#include <math.h>

#define N_NODES 50000
#define E_RAWN  600000
#define FEAT    64
#define HID     64
#define HEADS   4
#define NSUB    32
#define NGRAPH  128
#define NB_SCAN ((N_NODES + 255) / 256)   // 196
#define G2_NODES 128

__device__ __forceinline__ float leaky02(float v) { return v >= 0.f ? v : 0.2f * v; }
__device__ __forceinline__ float elu1(float v)    { return v > 0.f ? v : expm1f(v); }

// bf16 pack/unpack (RNE), 2 per uint
__device__ __forceinline__ unsigned bf2pack(float a, float b) {
    unsigned ua = __float_as_uint(a), ub = __float_as_uint(b);
    ua = (ua + 0x7FFFu + ((ua >> 16) & 1u)) >> 16;
    ub = (ub + 0x7FFFu + ((ub >> 16) & 1u)) >> 16;
    return ua | (ub << 16);
}
__device__ __forceinline__ float bflo(unsigned p) { return __uint_as_float(p << 16); }
__device__ __forceinline__ float bfhi(unsigned p) { return __uint_as_float(p & 0xFFFF0000u); }

// ---------- Phase A: substructure mean + attention MLP + softmax ----------
__global__ void k_subst_accum(const float* __restrict__ x,
                              float* __restrict__ ssum, float* __restrict__ scnt) {
    __shared__ float lsum[NSUB * FEAT];
    __shared__ float lcnt[NSUB];
    int tid = threadIdx.x;
    for (int i = tid; i < NSUB * FEAT; i += blockDim.x) lsum[i] = 0.f;
    if (tid < NSUB) lcnt[tid] = 0.f;
    __syncthreads();
    const int total = N_NODES * FEAT;
    for (int idx = blockIdx.x * blockDim.x + tid; idx < total; idx += gridDim.x * blockDim.x) {
        int node = idx >> 6, f = idx & 63;
        int sid = (int)x[node * FEAT + 5];
        atomicAdd(&lsum[sid * FEAT + f], x[idx]);
        if (f == 0) atomicAdd(&lcnt[sid], 1.f);
    }
    __syncthreads();
    for (int i = tid; i < NSUB * FEAT; i += blockDim.x) atomicAdd(&ssum[i], lsum[i]);
    if (tid < NSUB) atomicAdd(&scnt[tid], lcnt[tid]);
}

__global__ void k_subst_mlp(const float* __restrict__ ssum, const float* __restrict__ scnt,
                            const float* __restrict__ w_sa1, const float* __restrict__ b_sa1,
                            const float* __restrict__ w_sa2, const float* __restrict__ b_sa2,
                            float* __restrict__ wsub) {
    __shared__ float logits[NSUB];
    int s = threadIdx.x;   // 0..31
    float cnt = fmaxf(scnt[s], 1.f);
    float sm[FEAT];
    for (int k = 0; k < FEAT; k++) sm[k] = ssum[s * FEAT + k] / cnt;
    float logit = b_sa2[0];
    for (int j = 0; j < 32; j++) {
        float hj = b_sa1[j];
        for (int k = 0; k < FEAT; k++) hj += sm[k] * w_sa1[k * 32 + j];
        hj = leaky02(hj);
        logit += hj * w_sa2[j];
    }
    logits[s] = logit;
    __syncthreads();
    float m = -1e30f;
    for (int i = 0; i < NSUB; i++) m = fmaxf(m, logits[i]);
    float dsum = 0.f;
    for (int i = 0; i < NSUB; i++) dsum += expf(logits[i] - m);
    wsub[s] = expf(logits[s] - m) / dsum;
}

// ---------- Phase B: h1 = [x, atom_w] @ W1 (register-tiled, LDS x-tile) ----------
// h1 stored as bf16 (packed 2/uint, row = 128 uints). as1/ad1 from f32 accs (exact).
__global__ __launch_bounds__(256) void k_gemm1(const float* __restrict__ x,
                                               const float* __restrict__ wsub,
                                               const float* __restrict__ W1,
                                               const float* __restrict__ att_s1,
                                               const float* __restrict__ att_d1,
                                               unsigned* __restrict__ h1b,
                                               float* __restrict__ as1, float* __restrict__ ad1) {
    __shared__ float xs[65][68];
    int t = threadIdx.x;
    int gbase = blockIdx.x * 64;
    for (int idx = t; idx < 64 * 64; idx += 256) {
        int n = idx >> 6, f = idx & 63;
        int g = gbase + n;
        xs[f][n] = (g < N_NODES) ? x[(size_t)g * FEAT + f] : 0.f;
    }
    __syncthreads();
    if (t < 64) {
        int sid = (int)xs[5][t];
        xs[64][t] = wsub[sid & (NSUB - 1)];
    }
    __syncthreads();

    int m = t & 31, q = t >> 5;
    int c0 = m * 8, q8 = q * 8;
    float accs[64];
    #pragma unroll
    for (int i = 0; i < 64; ++i) accs[i] = 0.f;

    for (int k = 0; k < 65; ++k) {
        float4 wa = *(const float4*)(W1 + (size_t)k * 256 + c0);
        float4 wb = *(const float4*)(W1 + (size_t)k * 256 + c0 + 4);
        float4 xa = *(const float4*)(&xs[k][q8]);
        float4 xb = *(const float4*)(&xs[k][q8 + 4]);
        float wv[8] = {wa.x, wa.y, wa.z, wa.w, wb.x, wb.y, wb.z, wb.w};
        float xv[8] = {xa.x, xa.y, xa.z, xa.w, xb.x, xb.y, xb.z, xb.w};
        #pragma unroll
        for (int c = 0; c < 8; ++c)
            #pragma unroll
            for (int j = 0; j < 8; ++j)
                accs[c * 8 + j] += wv[c] * xv[j];
    }

    float atts[8], attd[8];
    #pragma unroll
    for (int c = 0; c < 8; ++c) { atts[c] = att_s1[c0 + c]; attd[c] = att_d1[c0 + c]; }
    int h = m >> 3;
    #pragma unroll
    for (int j = 0; j < 8; ++j) {
        int node = gbase + q8 + j;
        float ps = 0.f, pd = 0.f;
        #pragma unroll
        for (int c = 0; c < 8; ++c) { ps += accs[c * 8 + j] * atts[c]; pd += accs[c * 8 + j] * attd[c]; }
        ps += __shfl_xor(ps, 1, 64); pd += __shfl_xor(pd, 1, 64);
        ps += __shfl_xor(ps, 2, 64); pd += __shfl_xor(pd, 2, 64);
        ps += __shfl_xor(ps, 4, 64); pd += __shfl_xor(pd, 4, 64);
        if (node < N_NODES) {
            uint4 pk;
            pk.x = bf2pack(accs[0 * 8 + j], accs[1 * 8 + j]);
            pk.y = bf2pack(accs[2 * 8 + j], accs[3 * 8 + j]);
            pk.z = bf2pack(accs[4 * 8 + j], accs[5 * 8 + j]);
            pk.w = bf2pack(accs[6 * 8 + j], accs[7 * 8 + j]);
            *(uint4*)(h1b + (size_t)node * 128 + m * 4) = pk;
            if ((m & 7) == 0) { as1[node * 4 + h] = ps; ad1[node * 4 + h] = pd; }
        }
    }
}

// ---------- CSR build (by dst) ----------
__global__ void k_count(const int* __restrict__ dst, int* __restrict__ cnt) {
    int e = blockIdx.x * blockDim.x + threadIdx.x;
    if (e < E_RAWN) atomicAdd(&cnt[dst[e]], 1);
}

__global__ void k_scan1(const int* __restrict__ cnt, int* __restrict__ offs, int* __restrict__ bsum) {
    __shared__ int sd[256];
    int tid = threadIdx.x;
    int i = blockIdx.x * 256 + tid;
    int v = (i < N_NODES) ? cnt[i] : 0;
    sd[tid] = v;
    for (int off = 1; off < 256; off <<= 1) {
        __syncthreads();
        int tv = (tid >= off) ? sd[tid - off] : 0;
        __syncthreads();
        sd[tid] += tv;
    }
    __syncthreads();
    if (i < N_NODES) offs[i] = sd[tid] - v;
    if (tid == 255) bsum[blockIdx.x] = sd[255];
}

__global__ void k_scan2(int* __restrict__ bsum, int nb) {
    __shared__ int sd[256];
    int tid = threadIdx.x;
    int v = (tid < nb) ? bsum[tid] : 0;
    sd[tid] = v;
    for (int off = 1; off < 256; off <<= 1) {
        __syncthreads();
        int tv = (tid >= off) ? sd[tid - off] : 0;
        __syncthreads();
        sd[tid] += tv;
    }
    __syncthreads();
    if (tid < nb) bsum[tid] = sd[tid] - v;
}

__global__ void k_scan3(int* __restrict__ offs, const int* __restrict__ bsum) {
    int i = blockIdx.x * 256 + threadIdx.x;
    if (i < N_NODES) offs[i] += bsum[blockIdx.x];
    if (blockIdx.x == 0 && threadIdx.x == 0) offs[N_NODES] = E_RAWN;
}

__global__ void k_scatter(const int* __restrict__ src, const int* __restrict__ dst,
                          const int* __restrict__ offs, int* __restrict__ cur,
                          int* __restrict__ esrc) {
    int e = blockIdx.x * blockDim.x + threadIdx.x;
    if (e < E_RAWN) {
        int d = dst[e];
        int pos = offs[d] + atomicAdd(&cur[d], 1);
        esrc[pos] = src[e];
    }
}

// ---------- Phase D: GAT layer 1 aggregation — single pass, unroll 4, bf16 gather ----------
// No max-subtraction: d = sum(exp) accumulated alongside the weighted gather.
// w is uniform within each 16-lane head group, so d needs no cross-lane reduce.
__global__ __launch_bounds__(256) void k_gat1(const unsigned* __restrict__ h1b,
                                              const float* __restrict__ as1,
                                              const float* __restrict__ ad1,
                                              const int* __restrict__ offs,
                                              const int* __restrict__ esrc,
                                              const float* __restrict__ b1,
                                              float* __restrict__ hact) {
    int wave = threadIdx.x >> 6, lane = threadIdx.x & 63;
    int i = blockIdx.x * 4 + wave;
    if (i >= N_NODES) return;
    int beg = offs[i], end = offs[i + 1];
    int h = lane >> 4;
    float adv = ad1[i * 4 + h];
    float w0 = __expf(leaky02(as1[i * 4 + h] + adv));   // self loop
    uint2 hv = *(const uint2*)(h1b + (size_t)i * 128 + lane * 2);
    float4 acc = make_float4(w0 * bflo(hv.x), w0 * bfhi(hv.x), w0 * bflo(hv.y), w0 * bfhi(hv.y));
    float d = w0;
    int p = beg;
    for (; p + 3 < end; p += 4) {
        int s0 = esrc[p], s1 = esrc[p + 1], s2 = esrc[p + 2], s3 = esrc[p + 3];
        uint2 hA = *(const uint2*)(h1b + (size_t)s0 * 128 + lane * 2);
        uint2 hB = *(const uint2*)(h1b + (size_t)s1 * 128 + lane * 2);
        uint2 hC = *(const uint2*)(h1b + (size_t)s2 * 128 + lane * 2);
        uint2 hD = *(const uint2*)(h1b + (size_t)s3 * 128 + lane * 2);
        float a0 = as1[s0 * 4 + h], a1 = as1[s1 * 4 + h];
        float a2 = as1[s2 * 4 + h], a3 = as1[s3 * 4 + h];
        float wA = __expf(leaky02(a0 + adv));
        float wB = __expf(leaky02(a1 + adv));
        float wC = __expf(leaky02(a2 + adv));
        float wD = __expf(leaky02(a3 + adv));
        d += (wA + wB) + (wC + wD);
        acc.x += wA * bflo(hA.x) + wB * bflo(hB.x) + wC * bflo(hC.x) + wD * bflo(hD.x);
        acc.y += wA * bfhi(hA.x) + wB * bfhi(hB.x) + wC * bfhi(hC.x) + wD * bfhi(hD.x);
        acc.z += wA * bflo(hA.y) + wB * bflo(hB.y) + wC * bflo(hC.y) + wD * bflo(hD.y);
        acc.w += wA * bfhi(hA.y) + wB * bfhi(hB.y) + wC * bfhi(hC.y) + wD * bfhi(hD.y);
    }
    for (; p < end; ++p) {
        int s0 = esrc[p];
        uint2 hA = *(const uint2*)(h1b + (size_t)s0 * 128 + lane * 2);
        float wA = __expf(leaky02(as1[s0 * 4 + h] + adv));
        d += wA;
        acc.x += wA * bflo(hA.x);
        acc.y += wA * bfhi(hA.x);
        acc.z += wA * bflo(hA.y);
        acc.w += wA * bfhi(hA.y);
    }
    float inv = 1.f / (d + 1e-16f);
    float4 bb = *(const float4*)(b1 + lane * 4);
    float4 r;
    r.x = elu1(acc.x * inv + bb.x);
    r.y = elu1(acc.y * inv + bb.y);
    r.z = elu1(acc.z * inv + bb.z);
    r.w = elu1(acc.w * inv + bb.w);
    *(float4*)(hact + (size_t)i * 256 + lane * 4) = r;
}

// ---------- Phase E: h2 = hact @ W2 (register-tiled, K-chunked LDS) ----------
__global__ __launch_bounds__(256) void k_gemm2(const float* __restrict__ hact,
                                               const float* __restrict__ W2,
                                               const float* __restrict__ att_s2,
                                               const float* __restrict__ att_d2,
                                               float* __restrict__ h2,
                                               float* __restrict__ as2, float* __restrict__ ad2) {
    __shared__ float hs[G2_NODES][68];   // one 64-k chunk, [node][k], 272B rows
    int t = threadIdx.x;
    int gbase = blockIdx.x * G2_NODES;
    int m = t & 7, q = t >> 3;
    int c0 = m * 8, n0 = q * 4;
    float accs[32];                       // [col c][node j] = accs[c*4+j]
    #pragma unroll
    for (int i = 0; i < 32; ++i) accs[i] = 0.f;

    int sn = t >> 4;      // staging node (stride 16)
    int skq = t & 15;     // staging k-quad

    for (int kc = 0; kc < 4; ++kc) {
        __syncthreads();
        #pragma unroll
        for (int r = 0; r < 8; ++r) {
            int n = sn + r * 16;
            int g = gbase + n;
            float4 v = (g < N_NODES)
                ? *(const float4*)(hact + (size_t)g * 256 + kc * 64 + skq * 4)
                : make_float4(0.f, 0.f, 0.f, 0.f);
            *(float4*)(&hs[n][skq * 4]) = v;
        }
        __syncthreads();
        const float* Wc = W2 + (size_t)kc * 64 * 64;
        for (int kk = 0; kk < 16; ++kk) {
            float4 xv0 = *(const float4*)(&hs[n0 + 0][kk * 4]);
            float4 xv1 = *(const float4*)(&hs[n0 + 1][kk * 4]);
            float4 xv2 = *(const float4*)(&hs[n0 + 2][kk * 4]);
            float4 xv3 = *(const float4*)(&hs[n0 + 3][kk * 4]);
            const float* x0 = (const float*)&xv0;
            const float* x1 = (const float*)&xv1;
            const float* x2 = (const float*)&xv2;
            const float* x3 = (const float*)&xv3;
            #pragma unroll
            for (int jj = 0; jj < 4; ++jj) {
                int k = kk * 4 + jj;
                float4 wa = *(const float4*)(Wc + (size_t)k * 64 + c0);
                float4 wb = *(const float4*)(Wc + (size_t)k * 64 + c0 + 4);
                float wv[8] = {wa.x, wa.y, wa.z, wa.w, wb.x, wb.y, wb.z, wb.w};
                float xj[4] = {x0[jj], x1[jj], x2[jj], x3[jj]};
                #pragma unroll
                for (int c = 0; c < 8; ++c)
                    #pragma unroll
                    for (int j = 0; j < 4; ++j)
                        accs[c * 4 + j] += wv[c] * xj[j];
            }
        }
    }

    float atts[8], attd[8];
    #pragma unroll
    for (int c = 0; c < 8; ++c) { atts[c] = att_s2[c0 + c]; attd[c] = att_d2[c0 + c]; }
    #pragma unroll
    for (int j = 0; j < 4; ++j) {
        int node = gbase + n0 + j;
        float ps = 0.f, pd = 0.f;
        #pragma unroll
        for (int c = 0; c < 8; ++c) { ps += accs[c * 4 + j] * atts[c]; pd += accs[c * 4 + j] * attd[c]; }
        ps += __shfl_xor(ps, 1, 64); pd += __shfl_xor(pd, 1, 64);
        ps += __shfl_xor(ps, 2, 64); pd += __shfl_xor(pd, 2, 64);
        ps += __shfl_xor(ps, 4, 64); pd += __shfl_xor(pd, 4, 64);
        if (node < N_NODES) {
            *(float4*)(h2 + (size_t)node * 64 + c0) =
                make_float4(accs[0 * 4 + j], accs[1 * 4 + j], accs[2 * 4 + j], accs[3 * 4 + j]);
            *(float4*)(h2 + (size_t)node * 64 + c0 + 4) =
                make_float4(accs[4 * 4 + j], accs[5 * 4 + j], accs[6 * 4 + j], accs[7 * 4 + j]);
            if (m == 0) { as2[node] = ps; ad2[node] = pd; }
        }
    }
}

// ---------- Phase F: GAT layer 2 aggregation — single pass, unroll 4 ----------
__global__ __launch_bounds__(256) void k_gat2(const float* __restrict__ h2,
                                              const float* __restrict__ as2,
                                              const float* __restrict__ ad2,
                                              const int* __restrict__ offs,
                                              const int* __restrict__ esrc,
                                              float* __restrict__ rbuf) {
    int wave = threadIdx.x >> 6, lane = threadIdx.x & 63;
    int i = blockIdx.x * 4 + wave;
    if (i >= N_NODES) return;
    int beg = offs[i], end = offs[i + 1];
    float adv = ad2[i];
    float w0 = __expf(leaky02(as2[i] + adv));   // self loop
    float d = w0;
    float acc = w0 * h2[(size_t)i * 64 + lane];
    int p = beg;
    for (; p + 3 < end; p += 4) {
        int s0 = esrc[p], s1 = esrc[p + 1], s2 = esrc[p + 2], s3 = esrc[p + 3];
        float hA = h2[(size_t)s0 * 64 + lane];
        float hB = h2[(size_t)s1 * 64 + lane];
        float hC = h2[(size_t)s2 * 64 + lane];
        float hD = h2[(size_t)s3 * 64 + lane];
        float wA = __expf(leaky02(as2[s0] + adv));
        float wB = __expf(leaky02(as2[s1] + adv));
        float wC = __expf(leaky02(as2[s2] + adv));
        float wD = __expf(leaky02(as2[s3] + adv));
        d += (wA + wB) + (wC + wD);
        acc += wA * hA + wB * hB + wC * hC + wD * hD;
    }
    for (; p < end; ++p) {
        int s0 = esrc[p];
        float wA = __expf(leaky02(as2[s0] + adv));
        d += wA;
        acc += wA * h2[(size_t)s0 * 64 + lane];
    }
    rbuf[(size_t)i * 64 + lane] = acc / (d + 1e-16f);
}

// ---------- Phase G: pool per graph (batch sorted, binary search ranges) ----------
__device__ __forceinline__ int lower_bound_i(const int* a, int n, int v) {
    int lo = 0, hi = n;
    while (lo < hi) { int mid = (lo + hi) >> 1; if (a[mid] < v) lo = mid + 1; else hi = mid; }
    return lo;
}

__global__ void k_pool(const float* __restrict__ rbuf, const int* __restrict__ batch,
                       const float* __restrict__ b2, float* __restrict__ g) {
    __shared__ float red[4][64];
    int b = blockIdx.x;
    int lo = lower_bound_i(batch, N_NODES, b);
    int hi = lower_bound_i(batch, N_NODES, b + 1);
    int c = threadIdx.x & 63, rg = threadIdx.x >> 6;
    float s = 0.f;
    for (int r = lo + rg; r < hi; r += 4) s += rbuf[(size_t)r * 64 + c];
    red[rg][c] = s;
    __syncthreads();
    if (rg == 0) {
        float tot = red[0][c] + red[1][c] + red[2][c] + red[3][c] + (float)(hi - lo) * b2[c];
        g[(size_t)b * 64 + c] = tot;
    }
}

// ---------- Phase H: prediction head ----------
__global__ void k_head(const float* __restrict__ g,
                       const float* __restrict__ Wp1, const float* __restrict__ bp1,
                       const float* __restrict__ Wp2, const float* __restrict__ bp2,
                       float* __restrict__ out) {
    int t = threadIdx.x;
    if (t >= NGRAPH) return;
    float acc = bp2[0];
    for (int j = 0; j < 32; j++) {
        float hj = bp1[j];
        for (int k = 0; k < 64; k++) hj += g[(size_t)t * 64 + k] * Wp1[k * 32 + j];
        hj = elu1(hj);
        acc += hj * Wp2[j];
    }
    out[t] = acc;
}

extern "C" void kernel_launch(void* const* d_in, const int* in_sizes, int n_in,
                              void* d_out, int out_size, void* d_ws, size_t ws_size,
                              hipStream_t stream) {
    const float* x      = (const float*)d_in[0];
    const int*   edge   = (const int*)d_in[1];
    const int*   batch  = (const int*)d_in[2];
    const float* w_sa1  = (const float*)d_in[3];
    const float* b_sa1  = (const float*)d_in[4];
    const float* w_sa2  = (const float*)d_in[5];
    const float* b_sa2  = (const float*)d_in[6];
    const float* W1     = (const float*)d_in[7];
    const float* att_s1 = (const float*)d_in[8];
    const float* att_d1 = (const float*)d_in[9];
    const float* b1     = (const float*)d_in[10];
    const float* W2     = (const float*)d_in[11];
    const float* att_s2 = (const float*)d_in[12];
    const float* att_d2 = (const float*)d_in[13];
    const float* b2     = (const float*)d_in[14];
    const float* Wp1    = (const float*)d_in[15];
    const float* bp1    = (const float*)d_in[16];
    const float* Wp2    = (const float*)d_in[17];
    const float* bp2    = (const float*)d_in[18];
    float* out = (float*)d_out;

    const int* e_src = edge;
    const int* e_dst = edge + E_RAWN;

    char* base = (char*)d_ws;
    size_t off = 0;
    auto alloc = [&](size_t bytes) -> void* {
        void* p = base + off;
        off = (off + bytes + 255) & ~(size_t)255;
        return p;
    };
    float* ssum   = (float*)alloc((NSUB * FEAT + NSUB) * 4);
    float* scnt   = ssum + NSUB * FEAT;
    float* wsub   = (float*)alloc(NSUB * 4);
    float* as1    = (float*)alloc((size_t)N_NODES * 4 * 4);
    float* ad1    = (float*)alloc((size_t)N_NODES * 4 * 4);
    float* as2    = (float*)alloc((size_t)N_NODES * 4);
    float* ad2    = (float*)alloc((size_t)N_NODES * 4);
    int*   counts = (int*)alloc((size_t)N_NODES * 2 * 4);
    int*   cursor = counts + N_NODES;
    int*   offs   = (int*)alloc((size_t)(N_NODES + 1) * 4);
    int*   bsum   = (int*)alloc(256 * 4);
    int*   esrc   = (int*)alloc((size_t)E_RAWN * 4);
    float* gpool  = (float*)alloc((size_t)NGRAPH * HID * 4);
    unsigned* h1b = (unsigned*)alloc((size_t)N_NODES * 128 * 4);   // bf16-packed h1
    float* hact   = (float*)alloc((size_t)N_NODES * 256 * 4);
    float* h2     = (float*)alloc((size_t)N_NODES * 64 * 4);
    float* rbuf   = hact;   // overlay: hact dead after k_gemm2

    (void)hipMemsetAsync(ssum,   0, (NSUB * FEAT + NSUB) * 4, stream);
    (void)hipMemsetAsync(counts, 0, (size_t)N_NODES * 2 * 4, stream);

    k_subst_accum<<<256, 256, 0, stream>>>(x, ssum, scnt);
    k_subst_mlp<<<1, 32, 0, stream>>>(ssum, scnt, w_sa1, b_sa1, w_sa2, b_sa2, wsub);
    k_gemm1<<<(N_NODES + 63) / 64, 256, 0, stream>>>(x, wsub, W1, att_s1, att_d1, h1b, as1, ad1);

    k_count<<<(E_RAWN + 255) / 256, 256, 0, stream>>>(e_dst, counts);
    k_scan1<<<NB_SCAN, 256, 0, stream>>>(counts, offs, bsum);
    k_scan2<<<1, 256, 0, stream>>>(bsum, NB_SCAN);
    k_scan3<<<NB_SCAN, 256, 0, stream>>>(offs, bsum);
    k_scatter<<<(E_RAWN + 255) / 256, 256, 0, stream>>>(e_src, e_dst, offs, cursor, esrc);

    k_gat1<<<(N_NODES + 3) / 4, 256, 0, stream>>>(h1b, as1, ad1, offs, esrc, b1, hact);
    k_gemm2<<<(N_NODES + G2_NODES - 1) / G2_NODES, 256, 0, stream>>>(hact, W2, att_s2, att_d2, h2, as2, ad2);
    k_gat2<<<(N_NODES + 3) / 4, 256, 0, stream>>>(h2, as2, ad2, offs, esrc, rbuf);
    k_pool<<<NGRAPH, 256, 0, stream>>>(rbuf, batch, b2, gpool);
    k_head<<<1, 128, 0, stream>>>(gpool, Wp1, bp1, Wp2, bp2, out);
}